// Round 13
// baseline (376.419 us; speedup 1.0000x reference)
//
#include <hip/hip_runtime.h>
#include <hip/hip_bf16.h>
#include <stdint.h>

// ---------- types ----------
typedef __attribute__((ext_vector_type(8))) __bf16 bf16x8;
typedef __attribute__((ext_vector_type(8))) short short8v;
typedef __attribute__((ext_vector_type(4))) short short4v;
typedef __attribute__((ext_vector_type(4))) float f32x4;
typedef __attribute__((ext_vector_type(2))) uint32_t u32x2;
typedef __attribute__((ext_vector_type(4))) uint32_t u32x4;

__device__ __forceinline__ float bf2f(short u) {
  return __builtin_bit_cast(float, (uint32_t)((uint32_t)(uint16_t)u << 16));
}
__device__ __forceinline__ short f2bf(float f) {
  uint32_t x = __builtin_bit_cast(uint32_t, f);
  x += 0x7FFFu + ((x >> 16) & 1u);
  return (short)(x >> 16);
}
// packed f32->2xbf16 (RNE, identical rounding to f2bf). low16 = lo, high16 = hi.
__device__ __forceinline__ uint32_t cvtpk(float lo, float hi) {
  uint32_t r;
  asm("v_cvt_pk_bf16_f32 %0, %1, %2" : "=v"(r) : "v"(lo), "v"(hi));
  return r;
}
__device__ __forceinline__ f32x4 mfma16(short8v a, short8v b, f32x4 c) {
  return __builtin_amdgcn_mfma_f32_16x16x32_bf16(
      __builtin_bit_cast(bf16x8, a), __builtin_bit_cast(bf16x8, b), c, 0, 0, 0);
}
// XOR-swizzled LDS address (shorts), 16-slot window (conflict-free, round-6).
__device__ __forceinline__ int swz256(int row, int col) {
  return row * 256 + (col ^ ((row & 15) << 3));
}
__device__ __forceinline__ int swz128(int row, int col) {
  return row * 128 + (col ^ ((row & 15) << 3));
}

// ---------- merged prepack + qb: ONE launch ----------
// blocks [0, pp_blocks): weight prepack. blocks [pp_blocks, +512): qb.
struct PPDesc { const float* src; short* dst; int Ks, Ns, KT, NT, tile_base; };
struct PPArgs { PPDesc d[11]; int n_desc; int total_tiles; int pp_blocks; };

__global__ void prepack_all(PPArgs args, const float* __restrict__ qst,
                            const float* __restrict__ Wg1raw,
                            const float* __restrict__ bg1, float* __restrict__ qb) {
  if ((int)blockIdx.x >= args.pp_blocks) {
    // ---- qb path (32 batches/block) ----
    int c = threadIdx.x;
    int b0 = ((int)blockIdx.x - args.pp_blocks) * 32;
    float wcol[11];
#pragma unroll
    for (int k = 0; k < 11; ++k) wcol[k] = Wg1raw[(200 + k) * 256 + c];
    float bias = bg1[c];
#pragma unroll 1
    for (int bb = 0; bb < 32; ++bb) {
      int b = b0 + bb;
      float acc = bias;
#pragma unroll
      for (int k = 0; k < 11; ++k) acc += qst[b * 11 + k] * wcol[k];
      qb[b * 256 + c] = acc;
    }
    return;
  }
  // ---- prepack path ----
  int idx = blockIdx.x * 256 + threadIdx.x;
  int tile = idx >> 6;
  if (tile >= args.total_tiles) return;
  int lane = idx & 63;
  int e = 0;
  while (e + 1 < args.n_desc && args.d[e + 1].tile_base <= tile) ++e;
  const PPDesc D = args.d[e];
  int t = tile - D.tile_base;
  int kt = t % D.KT, nt = t / D.KT;
  int n = nt * 16 + (lane & 15);
  int kbase = kt * 32 + ((lane >> 4) * 8);
  short8v o;
#pragma unroll
  for (int j = 0; j < 8; ++j) {
    int k = kbase + j;
    o[j] = f2bf((k < D.Ks && n < D.Ns) ? D.src[k * D.Ns + n] : 0.f);
  }
  *(short8v*)&D.dst[((size_t)t * 64 + lane) * 8] = o;
}

// ---------- encoder: tabs[64 rows x 10] -> x -> u(bf16), v(bf16) ----------
// v14: L3 now ALSO swapped + packed u32x2 epilogue (was the last scalar-write
// epilogue: 32 ds_write_b16 + selects per thread -> 8 packed writes). col<100
// mask is whole-vector: 100%4==0 and c0 is 4-aligned, so c0<100 covers all 4
// lanes' cols; bias f32x4 load from bi3[c0] in-bounds (<=bi3[99]).
__launch_bounds__(256, 3)
__global__ void enc_kernel(const float* __restrict__ tabs,
    const float* __restrict__ bi1, const float* __restrict__ bi2, const float* __restrict__ bi3,
    const short* __restrict__ Wi1p, const short* __restrict__ Wi2p, const short* __restrict__ Wi3p,
    const short* __restrict__ Wap, const short* __restrict__ Wbp,
    short* __restrict__ u_g, short* __restrict__ v_g) {
  __shared__ __align__(16) short sIn[64 * 32];   // K padded 10->32
  __shared__ __align__(16) short sH1[64 * 256];  // swizzled; sX aliases this after L2
  __shared__ __align__(16) short sH2[64 * 128];  // swizzled
  short* sX = sH1;                               // reuse (stride 128, swizzled)
  const int tid = threadIdx.x;
  const int lane = tid & 63, w = tid >> 6, quad = lane >> 4, ll = lane & 15;
  const int xl = ll << 3;
  const int obj0 = blockIdx.x * 64;

  for (int idx = tid; idx < 64 * 32; idx += 256) {
    int r = idx >> 5, k = idx & 31;
    float v = (k < 10) ? tabs[(obj0 + r) * 10 + k] : 0.f;
    sIn[idx] = f2bf(v);
  }
  __syncthreads();

  // L1: relu(in @ Wi1 + bi1)  K=32(pad), N=256  (swapped; acc[mi=W-tile][nt=row-tile])
  {
    f32x4 acc[4][4];
#pragma unroll
    for (int mi = 0; mi < 4; ++mi) {
      f32x4 b4 = *(const f32x4*)&bi1[(w * 4 + mi) * 16 + quad * 4];
#pragma unroll
      for (int nt = 0; nt < 4; ++nt) acc[mi][nt] = b4;
    }
    short8v wv[4];
#pragma unroll
    for (int mi = 0; mi < 4; ++mi)
      wv[mi] = *(const short8v*)&Wi1p[((w * 4 + mi) * 64 + lane) * 8];
#pragma unroll
    for (int nt = 0; nt < 4; ++nt) {
      short8v a = *(const short8v*)&sIn[(nt * 16 + ll) * 32 + quad * 8];
#pragma unroll
      for (int mi = 0; mi < 4; ++mi) acc[mi][nt] = mfma16(wv[mi], a, acc[mi][nt]);
    }
#pragma unroll
    for (int mi = 0; mi < 4; ++mi) {
      int c0 = (w * 4 + mi) * 16 + quad * 4;
#pragma unroll
      for (int nt = 0; nt < 4; ++nt) {
        int row = nt * 16 + ll;
        f32x4 a = acc[mi][nt];
        u32x2 o = {cvtpk(fmaxf(a[0], 0.f), fmaxf(a[1], 0.f)),
                   cvtpk(fmaxf(a[2], 0.f), fmaxf(a[3], 0.f))};
        *(u32x2*)&sH1[row * 256 + (c0 ^ ((row & 15) << 3))] = o;
      }
    }
  }
  __syncthreads();

  // L2: relu(h1 @ Wi2 + bi2)  K=256, N=128  (swapped)
  {
    f32x4 acc[2][4];
#pragma unroll
    for (int mi = 0; mi < 2; ++mi) {
      f32x4 b4 = *(const f32x4*)&bi2[(w * 2 + mi) * 16 + quad * 4];
#pragma unroll
      for (int nt = 0; nt < 4; ++nt) acc[mi][nt] = b4;
    }
#pragma unroll 1
    for (int kt = 0; kt < 8; ++kt) {
      short8v wv[2];
#pragma unroll
      for (int mi = 0; mi < 2; ++mi)
        wv[mi] = *(const short8v*)&Wi2p[(((w * 2 + mi) * 8 + kt) * 64 + lane) * 8];
#pragma unroll
      for (int nt = 0; nt < 4; ++nt) {
        short8v a = *(const short8v*)&sH1[(nt * 16 + ll) * 256 + ((kt * 32 + quad * 8) ^ xl)];
#pragma unroll
        for (int mi = 0; mi < 2; ++mi) acc[mi][nt] = mfma16(wv[mi], a, acc[mi][nt]);
      }
    }
    __syncthreads();   // sH1 reads done (sX will overwrite it after L3)
#pragma unroll
    for (int mi = 0; mi < 2; ++mi) {
      int c0 = (w * 2 + mi) * 16 + quad * 4;
#pragma unroll
      for (int nt = 0; nt < 4; ++nt) {
        int row = nt * 16 + ll;
        f32x4 a = acc[mi][nt];
        u32x2 o = {cvtpk(fmaxf(a[0], 0.f), fmaxf(a[1], 0.f)),
                   cvtpk(fmaxf(a[2], 0.f), fmaxf(a[3], 0.f))};
        *(u32x2*)&sH2[row * 128 + (c0 ^ ((row & 15) << 3))] = o;
      }
    }
  }
  __syncthreads();

  // L3: x = h2 @ Wi3 + bi3 (NO relu)  K=128, N=128(pad, cols>=100 zero) -> sX
  // (swapped: lane = 4 consecutive cols of one row; whole-vector col<100 mask)
  {
    f32x4 acc[2][4] = {};
#pragma unroll 1
    for (int kt = 0; kt < 4; ++kt) {
      short8v wv[2];
#pragma unroll
      for (int mi = 0; mi < 2; ++mi)
        wv[mi] = *(const short8v*)&Wi3p[(((w * 2 + mi) * 4 + kt) * 64 + lane) * 8];
#pragma unroll
      for (int nt = 0; nt < 4; ++nt) {
        short8v a = *(const short8v*)&sH2[(nt * 16 + ll) * 128 + ((kt * 32 + quad * 8) ^ xl)];
#pragma unroll
        for (int mi = 0; mi < 2; ++mi) acc[mi][nt] = mfma16(wv[mi], a, acc[mi][nt]);
      }
    }
#pragma unroll
    for (int mi = 0; mi < 2; ++mi) {
      int c0 = (w * 2 + mi) * 16 + quad * 4;
      bool live = (c0 < 100);                       // covers c0..c0+3 (100%4==0)
      f32x4 b4 = live ? *(const f32x4*)&bi3[c0] : f32x4{0.f, 0.f, 0.f, 0.f};
#pragma unroll
      for (int nt = 0; nt < 4; ++nt) {
        int row = nt * 16 + ll;
        f32x4 a = acc[mi][nt];
        u32x2 o;
        if (live) {
          o = u32x2{cvtpk(a[0] + b4[0], a[1] + b4[1]),
                    cvtpk(a[2] + b4[2], a[3] + b4[3])};
        } else {
          o = u32x2{0u, 0u};
        }
        *(u32x2*)&sX[row * 128 + (c0 ^ ((row & 15) << 3))] = o;
      }
    }
  }
  __syncthreads();

  // L4: u = x @ Wa ; v = x @ Wb  (swapped: regs = 4 consecutive cols of one obj row)
#pragma unroll 1
  for (int pass = 0; pass < 2; ++pass) {
    const short* Wp = pass ? Wbp : Wap;
    short* outg = pass ? v_g : u_g;
    f32x4 acc[4][4] = {};
#pragma unroll 1
    for (int kt = 0; kt < 4; ++kt) {
      short8v wv[4];
#pragma unroll
      for (int mi = 0; mi < 4; ++mi)
        wv[mi] = *(const short8v*)&Wp[(((w * 4 + mi) * 4 + kt) * 64 + lane) * 8];
#pragma unroll
      for (int nt = 0; nt < 4; ++nt) {
        short8v xb = *(const short8v*)&sX[(nt * 16 + ll) * 128 + ((kt * 32 + quad * 8) ^ xl)];
#pragma unroll
        for (int mi = 0; mi < 4; ++mi) acc[mi][nt] = mfma16(wv[mi], xb, acc[mi][nt]);
      }
    }
#pragma unroll
    for (int mi = 0; mi < 4; ++mi) {
      int c0 = (w * 4 + mi) * 16 + quad * 4;
#pragma unroll
      for (int nt = 0; nt < 4; ++nt) {
        int obj = obj0 + nt * 16 + ll;
        f32x4 a = acc[mi][nt];
        u32x2 o = {cvtpk(a[0], a[1]), cvtpk(a[2], a[3])};
        *(u32x2*)&outg[(size_t)obj * 256 + c0] = o;
      }
    }
  }
}

// ---------- pair MLP v13 (unchanged control): zero-pad 144-row + isolated setprio ----------
// Sentinels: VGPR 56, LDS 73728, WRITE_SIZE exactly 16384 KB, dur ~221us.
__launch_bounds__(512, 4)
__global__ void pair_kernel(const short* __restrict__ u_g, const short* __restrict__ v_g,
    const float* __restrict__ qbp,
    const short* __restrict__ Wg2p, const short* __restrict__ Wg3p, const short* __restrict__ Wg4p,
    const float* __restrict__ bg2, const float* __restrict__ bg3, const float* __restrict__ bg4,
    float* __restrict__ g_g) {
  __shared__ __align__(16) short sH[144 * 256];  // 73728 B, swizzled, no pad rows
  const int tid = threadIdx.x;
  const int lane = tid & 63, w = tid >> 6, quad = lane >> 4, ll = lane & 15;
  const int xl = ll << 3;
  const int b0 = blockIdx.x * 4;

  // h1 = relu((u[j]+v[i]) + qb); row = bb*36 + i*6 + j in [0,144); 4608 = 9x512 chunks.
#pragma unroll 1
  for (int it = 0; it < 9; ++it) {
    int vi = it * 512 + tid;
    int row = vi >> 5, c8 = (vi & 31) * 8;
    int bb = row / 36, p = row - bb * 36;
    int i2 = p / 6, j2 = p - i2 * 6;
    short8v u8 = *(const short8v*)&u_g[(size_t)((b0 + bb) * 6 + j2) * 256 + c8];
    short8v v8 = *(const short8v*)&v_g[(size_t)((b0 + bb) * 6 + i2) * 256 + c8];
    f32x4 qa = *(const f32x4*)&qbp[(size_t)(b0 + bb) * 256 + c8];
    f32x4 qc = *(const f32x4*)&qbp[(size_t)(b0 + bb) * 256 + c8 + 4];
    float m[8];
#pragma unroll
    for (int e = 0; e < 4; ++e) m[e] = fmaxf(bf2f(u8[e]) + bf2f(v8[e]) + qa[e], 0.f);
#pragma unroll
    for (int e = 0; e < 4; ++e) m[4 + e] = fmaxf(bf2f(u8[4 + e]) + bf2f(v8[4 + e]) + qc[e], 0.f);
    u32x4 o = {cvtpk(m[0], m[1]), cvtpk(m[2], m[3]), cvtpk(m[4], m[5]), cvtpk(m[6], m[7])};
    *(u32x4*)&sH[row * 256 + (c8 ^ ((row & 15) << 3))] = o;
  }
  __syncthreads();

  f32x4 acc[9][2];

  // L1, L2: swapped operands, in-place sH; every wave: all 9 row-tiles x ni=2 cols.
#pragma unroll 1
  for (int L = 0; L < 2; ++L) {
    const short* __restrict__ Wp = L ? Wg3p : Wg2p;
    const float* __restrict__ bp = L ? bg3 : bg2;
#pragma unroll
    for (int ni = 0; ni < 2; ++ni) {
      f32x4 b4 = *(const f32x4*)&bp[(w * 2 + ni) * 16 + quad * 4];
#pragma unroll
      for (int mt = 0; mt < 9; ++mt) acc[mt][ni] = b4;
    }
#pragma unroll 1
    for (int kt = 0; kt < 8; ++kt) {
      short8v wv[2];
#pragma unroll
      for (int ni = 0; ni < 2; ++ni)
        wv[ni] = *(const short8v*)&Wp[(((w * 2 + ni) * 8 + kt) * 64 + lane) * 8];
      __builtin_amdgcn_s_setprio(1);
#pragma unroll
      for (int mt = 0; mt < 9; ++mt) {
        short8v h = *(const short8v*)&sH[(mt * 16 + ll) * 256 + ((kt * 32 + quad * 8) ^ xl)];
#pragma unroll
        for (int ni = 0; ni < 2; ++ni) acc[mt][ni] = mfma16(wv[ni], h, acc[mt][ni]);
      }
      __builtin_amdgcn_s_setprio(0);
    }
    __syncthreads();  // all reads of sH done before in-place overwrite
#pragma unroll
    for (int ni = 0; ni < 2; ++ni) {
      int c0 = (w * 2 + ni) * 16 + quad * 4;
#pragma unroll
      for (int mt = 0; mt < 9; ++mt) {
        int row = mt * 16 + ll;
        f32x4 a = acc[mt][ni];
        u32x2 o = {cvtpk(fmaxf(a[0], 0.f), fmaxf(a[1], 0.f)),
                   cvtpk(fmaxf(a[2], 0.f), fmaxf(a[3], 0.f))};
        *(u32x2*)&sH[row * 256 + (c0 ^ ((row & 15) << 3))] = o;
      }
    }
    __syncthreads();
  }

  // L3: original order (lane = 4 rows of one col), bias in acc; pool fused in epilogue.
  {
#pragma unroll
    for (int ni = 0; ni < 2; ++ni) {
      float b = bg4[(w * 2 + ni) * 16 + ll];
#pragma unroll
      for (int mt = 0; mt < 9; ++mt) acc[mt][ni] = f32x4{b, b, b, b};
    }
#pragma unroll 1
    for (int kt = 0; kt < 8; ++kt) {
      short8v wv[2];
#pragma unroll
      for (int ni = 0; ni < 2; ++ni)
        wv[ni] = *(const short8v*)&Wg4p[(((w * 2 + ni) * 8 + kt) * 64 + lane) * 8];
      __builtin_amdgcn_s_setprio(1);
#pragma unroll
      for (int mt = 0; mt < 9; ++mt) {
        short8v a = *(const short8v*)&sH[(mt * 16 + ll) * 256 + ((kt * 32 + quad * 8) ^ xl)];
#pragma unroll
        for (int ni = 0; ni < 2; ++ni) acc[mt][ni] = mfma16(a, wv[ni], acc[mt][ni]);
      }
      __builtin_amdgcn_s_setprio(0);
    }
    // register-only pool. Lane rows: rr = mt*16 + quad*4 (+r) in [0,144); batch = rr/36.
#pragma unroll
    for (int ni = 0; ni < 2; ++ni) {
      int col = (w * 2 + ni) * 16 + ll;
      float s0 = 0.f, s1 = 0.f, s2 = 0.f, s3 = 0.f;
#pragma unroll
      for (int mt = 0; mt < 9; ++mt) {
        int rr = mt * 16 + quad * 4;
        float t = 0.f;
#pragma unroll
        for (int r = 0; r < 4; ++r) t += fmaxf(acc[mt][ni][r], 0.f);
        if (rr < 36) s0 += t;
        else if (rr < 72) s1 += t;
        else if (rr < 108) s2 += t;
        else s3 += t;
      }
      s0 += __shfl_xor(s0, 16, 64); s0 += __shfl_xor(s0, 32, 64);
      s1 += __shfl_xor(s1, 16, 64); s1 += __shfl_xor(s1, 32, 64);
      s2 += __shfl_xor(s2, 16, 64); s2 += __shfl_xor(s2, 32, 64);
      s3 += __shfl_xor(s3, 16, 64); s3 += __shfl_xor(s3, 32, 64);
      if (quad == 0) {
        g_g[(size_t)(b0 + 0) * 256 + col] = s0;
        g_g[(size_t)(b0 + 1) * 256 + col] = s1;
        g_g[(size_t)(b0 + 2) * 256 + col] = s2;
        g_g[(size_t)(b0 + 3) * 256 + col] = s3;
      }
    }
  }
}

// ---------- head helper: MTx16 rows x 256 @ 256x256 + bias + relu, LDS->LDS ----------
template<int MT>
__device__ __forceinline__ void gemmMx256(const short* sInp, short* sOut,
    const short* __restrict__ Wp, const float* __restrict__ bias,
    int w, int lane, int quad, int ll, int xl) {
  f32x4 acc[MT][4] = {};
#pragma unroll 1
  for (int kt = 0; kt < 8; ++kt) {
    short8v b[4];
#pragma unroll
    for (int ni = 0; ni < 4; ++ni)
      b[ni] = *(const short8v*)&Wp[(((w * 4 + ni) * 8 + kt) * 64 + lane) * 8];
#pragma unroll
    for (int mt = 0; mt < MT; ++mt) {
      short8v a = *(const short8v*)&sInp[(mt * 16 + ll) * 256 + ((kt * 32 + quad * 8) ^ xl)];
#pragma unroll
      for (int ni = 0; ni < 4; ++ni) acc[mt][ni] = mfma16(a, b[ni], acc[mt][ni]);
    }
  }
#pragma unroll
  for (int ni = 0; ni < 4; ++ni) {
    int col = (w * 4 + ni) * 16 + ll;
    float bv = bias[col];
#pragma unroll
    for (int mt = 0; mt < MT; ++mt)
#pragma unroll
      for (int r = 0; r < 4; ++r) {
        int row = mt * 16 + quad * 4 + r;
        sOut[swz256(row, col)] = f2bf(fmaxf(acc[mt][ni][r] + bv, 0.f));
      }
  }
}

// ---------- head v2: 16 batches/block, 1024 blocks (2x CU coverage) ----------
__launch_bounds__(256, 4)
__global__ void head_kernel(const float* __restrict__ g_g,
    const short* __restrict__ Wfp, const float* __restrict__ bf_,
    const short* __restrict__ Wo1p, const float* __restrict__ bo1,
    const short* __restrict__ Wo2p, const float* __restrict__ bo2,
    float* __restrict__ outp) {
  __shared__ __align__(16) short sA[16 * 256];
  __shared__ __align__(16) short sB[16 * 256];
  __shared__ float sL[16 * 16];
  const int tid = threadIdx.x;
  const int lane = tid & 63, w = tid >> 6, quad = lane >> 4, ll = lane & 15;
  const int xl = ll << 3;
  const int b0 = blockIdx.x * 16;

#pragma unroll 1
  for (int it = 0; it < 4; ++it) {
    int vi = it * 256 + tid;
    int row = vi >> 6, c4 = (vi & 63) * 4;
    f32x4 gv = *(const f32x4*)&g_g[(size_t)(b0 + row) * 256 + c4];
    short4v o;
#pragma unroll
    for (int e = 0; e < 4; ++e) o[e] = f2bf(gv[e]);
    *(short4v*)&sA[row * 256 + (c4 ^ ((row & 15) << 3))] = o;
  }
  __syncthreads();
  gemmMx256<1>(sA, sB, Wfp, bf_, w, lane, quad, ll, xl);
  __syncthreads();
  gemmMx256<1>(sB, sA, Wo1p, bo1, w, lane, quad, ll, xl);
  __syncthreads();
  if (w == 0) {
    f32x4 acc = {};
#pragma unroll 1
    for (int kt = 0; kt < 8; ++kt) {
      short8v b = *(const short8v*)&Wo2p[(kt * 64 + lane) * 8];
      short8v a = *(const short8v*)&sA[ll * 256 + ((kt * 32 + quad * 8) ^ xl)];
      acc = mfma16(a, b, acc);
    }
#pragma unroll
    for (int r = 0; r < 4; ++r) {
      int row = quad * 4 + r;
      sL[row * 16 + ll] = acc[r] + ((ll < 10) ? bo2[ll] : 0.f);
    }
  }
  __syncthreads();
  if (tid < 16) {
    float m = -1e30f;
#pragma unroll
    for (int c = 0; c < 10; ++c) m = fmaxf(m, sL[tid * 16 + c]);
    float s = 0.f;
#pragma unroll
    for (int c = 0; c < 10; ++c) s += expf(sL[tid * 16 + c] - m);
    float ls = logf(s) + m;
#pragma unroll
    for (int c = 0; c < 10; ++c) outp[(size_t)(b0 + tid) * 10 + c] = sL[tid * 16 + c] - ls;
  }
}

extern "C" void kernel_launch(void* const* d_in, const int* in_sizes, int n_in,
                              void* d_out, int out_size, void* d_ws, size_t ws_size,
                              hipStream_t stream) {
  const float* tabs = (const float*)d_in[0];
  const float* qst  = (const float*)d_in[1];
  const float* Wi1 = (const float*)d_in[2];  const float* bi1 = (const float*)d_in[3];
  const float* Wi2 = (const float*)d_in[4];  const float* bi2 = (const float*)d_in[5];
  const float* Wi3 = (const float*)d_in[6];  const float* bi3 = (const float*)d_in[7];
  const float* Wg1 = (const float*)d_in[8];  const float* bg1 = (const float*)d_in[9];
  const float* Wg2 = (const float*)d_in[10]; const float* bg2 = (const float*)d_in[11];
  const float* Wg3 = (const float*)d_in[12]; const float* bg3 = (const float*)d_in[13];
  const float* Wg4 = (const float*)d_in[14]; const float* bg4 = (const float*)d_in[15];
  const float* Wf  = (const float*)d_in[16]; const float* bf_ = (const float*)d_in[17];
  const float* Wo1 = (const float*)d_in[18]; const float* bo1 = (const float*)d_in[19];
  const float* Wo2 = (const float*)d_in[20]; const float* bo2 = (const float*)d_in[21];
  float* outp = (float*)d_out;
  (void)in_sizes; (void)n_in; (void)out_size; (void)ws_size;

  char* ws = (char*)d_ws;
  size_t off = 0;
  auto alloc = [&](size_t bytes) { void* p = ws + off; off += (bytes + 255) & ~(size_t)255; return p; };
  const size_t BN = 16384ull * 6;
  short* u_g = (short*)alloc(BN * 256 * 2);
  short* v_g = (short*)alloc(BN * 256 * 2);
  float* qb  = (float*)alloc(16384ull * 256 * 4);
  float* g_g = (float*)alloc(16384ull * 256 * 4);
  short* Wi1p = (short*)alloc(16 * 1 * 64 * 8 * 2);
  short* Wi2p = (short*)alloc(8 * 8 * 64 * 8 * 2);
  short* Wi3p = (short*)alloc(8 * 4 * 64 * 8 * 2);
  short* Wap  = (short*)alloc(16 * 4 * 64 * 8 * 2);
  short* Wbp  = (short*)alloc(16 * 4 * 64 * 8 * 2);
  short* Wg2p = (short*)alloc(16 * 8 * 64 * 8 * 2);
  short* Wg3p = (short*)alloc(16 * 8 * 64 * 8 * 2);
  short* Wg4p = (short*)alloc(16 * 8 * 64 * 8 * 2);
  short* Wfp  = (short*)alloc(16 * 8 * 64 * 8 * 2);
  short* Wo1p = (short*)alloc(16 * 8 * 64 * 8 * 2);
  short* Wo2p = (short*)alloc(1 * 8 * 64 * 8 * 2);

  PPArgs pa;
  int tb = 0, nd = 0;
  auto add = [&](const float* src, short* dst, int Ks, int Ns, int KT, int NT) {
    pa.d[nd++] = PPDesc{src, dst, Ks, Ns, KT, NT, tb};
    tb += KT * NT;
  };
  add(Wi1, Wi1p, 10, 256, 1, 16);
  add(Wi2, Wi2p, 256, 128, 8, 8);
  add(Wi3, Wi3p, 128, 100, 4, 8);
  add(Wg1,             Wap, 100, 256, 4, 16);
  add(Wg1 + 100 * 256, Wbp, 100, 256, 4, 16);
  add(Wg2, Wg2p, 256, 256, 8, 16);
  add(Wg3, Wg3p, 256, 256, 8, 16);
  add(Wg4, Wg4p, 256, 256, 8, 16);
  add(Wf,  Wfp,  256, 256, 8, 16);
  add(Wo1, Wo1p, 256, 256, 8, 16);
  add(Wo2, Wo2p, 256, 10, 8, 1);
  pa.n_desc = nd;
  pa.total_tiles = tb;
  pa.pp_blocks = (tb * 64 + 255) / 256;
  // merged prepack + qb: one launch, qb runs concurrent with weight prepack
  prepack_all<<<pa.pp_blocks + 512, 256, 0, stream>>>(pa, qst, Wg1, bg1, qb);

  enc_kernel<<<1536, 256, 0, stream>>>(tabs, bi1, bi2, bi3, Wi1p, Wi2p, Wi3p, Wap, Wbp, u_g, v_g);
  pair_kernel<<<4096, 512, 0, stream>>>(u_g, v_g, qb, Wg2p, Wg3p, Wg4p, bg2, bg3, bg4, g_g);
  head_kernel<<<1024, 256, 0, stream>>>(g_g, Wfp, bf_, Wo1p, bo1, Wo2p, bo2, outp);
}

// Round 14
// 370.891 us; speedup vs baseline: 1.0149x; 1.0149x over previous
//
#include <hip/hip_runtime.h>
#include <hip/hip_bf16.h>
#include <stdint.h>

// ---------- types ----------
typedef __attribute__((ext_vector_type(8))) __bf16 bf16x8;
typedef __attribute__((ext_vector_type(8))) short short8v;
typedef __attribute__((ext_vector_type(4))) short short4v;
typedef __attribute__((ext_vector_type(4))) float f32x4;
typedef __attribute__((ext_vector_type(2))) uint32_t u32x2;
typedef __attribute__((ext_vector_type(4))) uint32_t u32x4;

__device__ __forceinline__ float bf2f(short u) {
  return __builtin_bit_cast(float, (uint32_t)((uint32_t)(uint16_t)u << 16));
}
__device__ __forceinline__ short f2bf(float f) {
  uint32_t x = __builtin_bit_cast(uint32_t, f);
  x += 0x7FFFu + ((x >> 16) & 1u);
  return (short)(x >> 16);
}
// packed f32->2xbf16 (RNE, identical rounding to f2bf). low16 = lo, high16 = hi.
__device__ __forceinline__ uint32_t cvtpk(float lo, float hi) {
  uint32_t r;
  asm("v_cvt_pk_bf16_f32 %0, %1, %2" : "=v"(r) : "v"(lo), "v"(hi));
  return r;
}
__device__ __forceinline__ f32x4 mfma16(short8v a, short8v b, f32x4 c) {
  return __builtin_amdgcn_mfma_f32_16x16x32_bf16(
      __builtin_bit_cast(bf16x8, a), __builtin_bit_cast(bf16x8, b), c, 0, 0, 0);
}
// XOR-swizzled LDS address (shorts), 16-slot window (conflict-free, round-6).
__device__ __forceinline__ int swz256(int row, int col) {
  return row * 256 + (col ^ ((row & 15) << 3));
}
__device__ __forceinline__ int swz128(int row, int col) {
  return row * 128 + (col ^ ((row & 15) << 3));
}

// ---------- merged prepack + qb: ONE launch ----------
// blocks [0, pp_blocks): weight prepack. blocks [pp_blocks, +512): qb.
struct PPDesc { const float* src; short* dst; int Ks, Ns, KT, NT, tile_base; };
struct PPArgs { PPDesc d[11]; int n_desc; int total_tiles; int pp_blocks; };

__global__ void prepack_all(PPArgs args, const float* __restrict__ qst,
                            const float* __restrict__ Wg1raw,
                            const float* __restrict__ bg1, float* __restrict__ qb) {
  if ((int)blockIdx.x >= args.pp_blocks) {
    // ---- qb path (32 batches/block) ----
    int c = threadIdx.x;
    int b0 = ((int)blockIdx.x - args.pp_blocks) * 32;
    float wcol[11];
#pragma unroll
    for (int k = 0; k < 11; ++k) wcol[k] = Wg1raw[(200 + k) * 256 + c];
    float bias = bg1[c];
#pragma unroll 1
    for (int bb = 0; bb < 32; ++bb) {
      int b = b0 + bb;
      float acc = bias;
#pragma unroll
      for (int k = 0; k < 11; ++k) acc += qst[b * 11 + k] * wcol[k];
      qb[b * 256 + c] = acc;
    }
    return;
  }
  // ---- prepack path ----
  int idx = blockIdx.x * 256 + threadIdx.x;
  int tile = idx >> 6;
  if (tile >= args.total_tiles) return;
  int lane = idx & 63;
  int e = 0;
  while (e + 1 < args.n_desc && args.d[e + 1].tile_base <= tile) ++e;
  const PPDesc D = args.d[e];
  int t = tile - D.tile_base;
  int kt = t % D.KT, nt = t / D.KT;
  int n = nt * 16 + (lane & 15);
  int kbase = kt * 32 + ((lane >> 4) * 8);
  short8v o;
#pragma unroll
  for (int j = 0; j < 8; ++j) {
    int k = kbase + j;
    o[j] = f2bf((k < D.Ks && n < D.Ns) ? D.src[k * D.Ns + n] : 0.f);
  }
  *(short8v*)&D.dst[((size_t)t * 64 + lane) * 8] = o;
}

// ---------- encoder: tabs[64 rows x 10] -> x -> u(bf16), v(bf16) ----------
// L3 swapped + packed u32x2 epilogue (v14); whole-vector col<100 mask.
__launch_bounds__(256, 3)
__global__ void enc_kernel(const float* __restrict__ tabs,
    const float* __restrict__ bi1, const float* __restrict__ bi2, const float* __restrict__ bi3,
    const short* __restrict__ Wi1p, const short* __restrict__ Wi2p, const short* __restrict__ Wi3p,
    const short* __restrict__ Wap, const short* __restrict__ Wbp,
    short* __restrict__ u_g, short* __restrict__ v_g) {
  __shared__ __align__(16) short sIn[64 * 32];   // K padded 10->32
  __shared__ __align__(16) short sH1[64 * 256];  // swizzled; sX aliases this after L2
  __shared__ __align__(16) short sH2[64 * 128];  // swizzled
  short* sX = sH1;                               // reuse (stride 128, swizzled)
  const int tid = threadIdx.x;
  const int lane = tid & 63, w = tid >> 6, quad = lane >> 4, ll = lane & 15;
  const int xl = ll << 3;
  const int obj0 = blockIdx.x * 64;

  for (int idx = tid; idx < 64 * 32; idx += 256) {
    int r = idx >> 5, k = idx & 31;
    float v = (k < 10) ? tabs[(obj0 + r) * 10 + k] : 0.f;
    sIn[idx] = f2bf(v);
  }
  __syncthreads();

  // L1: relu(in @ Wi1 + bi1)  K=32(pad), N=256  (swapped; acc[mi=W-tile][nt=row-tile])
  {
    f32x4 acc[4][4];
#pragma unroll
    for (int mi = 0; mi < 4; ++mi) {
      f32x4 b4 = *(const f32x4*)&bi1[(w * 4 + mi) * 16 + quad * 4];
#pragma unroll
      for (int nt = 0; nt < 4; ++nt) acc[mi][nt] = b4;
    }
    short8v wv[4];
#pragma unroll
    for (int mi = 0; mi < 4; ++mi)
      wv[mi] = *(const short8v*)&Wi1p[((w * 4 + mi) * 64 + lane) * 8];
#pragma unroll
    for (int nt = 0; nt < 4; ++nt) {
      short8v a = *(const short8v*)&sIn[(nt * 16 + ll) * 32 + quad * 8];
#pragma unroll
      for (int mi = 0; mi < 4; ++mi) acc[mi][nt] = mfma16(wv[mi], a, acc[mi][nt]);
    }
#pragma unroll
    for (int mi = 0; mi < 4; ++mi) {
      int c0 = (w * 4 + mi) * 16 + quad * 4;
#pragma unroll
      for (int nt = 0; nt < 4; ++nt) {
        int row = nt * 16 + ll;
        f32x4 a = acc[mi][nt];
        u32x2 o = {cvtpk(fmaxf(a[0], 0.f), fmaxf(a[1], 0.f)),
                   cvtpk(fmaxf(a[2], 0.f), fmaxf(a[3], 0.f))};
        *(u32x2*)&sH1[row * 256 + (c0 ^ ((row & 15) << 3))] = o;
      }
    }
  }
  __syncthreads();

  // L2: relu(h1 @ Wi2 + bi2)  K=256, N=128  (swapped)
  {
    f32x4 acc[2][4];
#pragma unroll
    for (int mi = 0; mi < 2; ++mi) {
      f32x4 b4 = *(const f32x4*)&bi2[(w * 2 + mi) * 16 + quad * 4];
#pragma unroll
      for (int nt = 0; nt < 4; ++nt) acc[mi][nt] = b4;
    }
#pragma unroll 1
    for (int kt = 0; kt < 8; ++kt) {
      short8v wv[2];
#pragma unroll
      for (int mi = 0; mi < 2; ++mi)
        wv[mi] = *(const short8v*)&Wi2p[(((w * 2 + mi) * 8 + kt) * 64 + lane) * 8];
#pragma unroll
      for (int nt = 0; nt < 4; ++nt) {
        short8v a = *(const short8v*)&sH1[(nt * 16 + ll) * 256 + ((kt * 32 + quad * 8) ^ xl)];
#pragma unroll
        for (int mi = 0; mi < 2; ++mi) acc[mi][nt] = mfma16(wv[mi], a, acc[mi][nt]);
      }
    }
    __syncthreads();   // sH1 reads done (sX will overwrite it after L3)
#pragma unroll
    for (int mi = 0; mi < 2; ++mi) {
      int c0 = (w * 2 + mi) * 16 + quad * 4;
#pragma unroll
      for (int nt = 0; nt < 4; ++nt) {
        int row = nt * 16 + ll;
        f32x4 a = acc[mi][nt];
        u32x2 o = {cvtpk(fmaxf(a[0], 0.f), fmaxf(a[1], 0.f)),
                   cvtpk(fmaxf(a[2], 0.f), fmaxf(a[3], 0.f))};
        *(u32x2*)&sH2[row * 128 + (c0 ^ ((row & 15) << 3))] = o;
      }
    }
  }
  __syncthreads();

  // L3: x = h2 @ Wi3 + bi3 (NO relu)  K=128, N=128(pad, cols>=100 zero) -> sX
  // (swapped: lane = 4 consecutive cols of one row; whole-vector col<100 mask)
  {
    f32x4 acc[2][4] = {};
#pragma unroll 1
    for (int kt = 0; kt < 4; ++kt) {
      short8v wv[2];
#pragma unroll
      for (int mi = 0; mi < 2; ++mi)
        wv[mi] = *(const short8v*)&Wi3p[(((w * 2 + mi) * 4 + kt) * 64 + lane) * 8];
#pragma unroll
      for (int nt = 0; nt < 4; ++nt) {
        short8v a = *(const short8v*)&sH2[(nt * 16 + ll) * 128 + ((kt * 32 + quad * 8) ^ xl)];
#pragma unroll
        for (int mi = 0; mi < 2; ++mi) acc[mi][nt] = mfma16(wv[mi], a, acc[mi][nt]);
      }
    }
#pragma unroll
    for (int mi = 0; mi < 2; ++mi) {
      int c0 = (w * 2 + mi) * 16 + quad * 4;
      bool live = (c0 < 100);                       // covers c0..c0+3 (100%4==0)
      f32x4 b4 = live ? *(const f32x4*)&bi3[c0] : f32x4{0.f, 0.f, 0.f, 0.f};
#pragma unroll
      for (int nt = 0; nt < 4; ++nt) {
        int row = nt * 16 + ll;
        f32x4 a = acc[mi][nt];
        u32x2 o;
        if (live) {
          o = u32x2{cvtpk(a[0] + b4[0], a[1] + b4[1]),
                    cvtpk(a[2] + b4[2], a[3] + b4[3])};
        } else {
          o = u32x2{0u, 0u};
        }
        *(u32x2*)&sX[row * 128 + (c0 ^ ((row & 15) << 3))] = o;
      }
    }
  }
  __syncthreads();

  // L4: u = x @ Wa ; v = x @ Wb  (swapped: regs = 4 consecutive cols of one obj row)
#pragma unroll 1
  for (int pass = 0; pass < 2; ++pass) {
    const short* Wp = pass ? Wbp : Wap;
    short* outg = pass ? v_g : u_g;
    f32x4 acc[4][4] = {};
#pragma unroll 1
    for (int kt = 0; kt < 4; ++kt) {
      short8v wv[4];
#pragma unroll
      for (int mi = 0; mi < 4; ++mi)
        wv[mi] = *(const short8v*)&Wp[(((w * 4 + mi) * 4 + kt) * 64 + lane) * 8];
#pragma unroll
      for (int nt = 0; nt < 4; ++nt) {
        short8v xb = *(const short8v*)&sX[(nt * 16 + ll) * 128 + ((kt * 32 + quad * 8) ^ xl)];
#pragma unroll
        for (int mi = 0; mi < 4; ++mi) acc[mi][nt] = mfma16(wv[mi], xb, acc[mi][nt]);
      }
    }
#pragma unroll
    for (int mi = 0; mi < 4; ++mi) {
      int c0 = (w * 4 + mi) * 16 + quad * 4;
#pragma unroll
      for (int nt = 0; nt < 4; ++nt) {
        int obj = obj0 + nt * 16 + ll;
        f32x4 a = acc[mi][nt];
        u32x2 o = {cvtpk(a[0], a[1]), cvtpk(a[2], a[3])};
        *(u32x2*)&outg[(size_t)obj * 256 + c0] = o;
      }
    }
  }
}

// ---------- pair MLP v13 (unchanged control): zero-pad 144-row + isolated setprio ----------
// Sentinels: VGPR 56, LDS 73728, WRITE_SIZE exactly 16384 KB, dur ~221us.
__launch_bounds__(512, 4)
__global__ void pair_kernel(const short* __restrict__ u_g, const short* __restrict__ v_g,
    const float* __restrict__ qbp,
    const short* __restrict__ Wg2p, const short* __restrict__ Wg3p, const short* __restrict__ Wg4p,
    const float* __restrict__ bg2, const float* __restrict__ bg3, const float* __restrict__ bg4,
    float* __restrict__ g_g) {
  __shared__ __align__(16) short sH[144 * 256];  // 73728 B, swizzled, no pad rows
  const int tid = threadIdx.x;
  const int lane = tid & 63, w = tid >> 6, quad = lane >> 4, ll = lane & 15;
  const int xl = ll << 3;
  const int b0 = blockIdx.x * 4;

  // h1 = relu((u[j]+v[i]) + qb); row = bb*36 + i*6 + j in [0,144); 4608 = 9x512 chunks.
#pragma unroll 1
  for (int it = 0; it < 9; ++it) {
    int vi = it * 512 + tid;
    int row = vi >> 5, c8 = (vi & 31) * 8;
    int bb = row / 36, p = row - bb * 36;
    int i2 = p / 6, j2 = p - i2 * 6;
    short8v u8 = *(const short8v*)&u_g[(size_t)((b0 + bb) * 6 + j2) * 256 + c8];
    short8v v8 = *(const short8v*)&v_g[(size_t)((b0 + bb) * 6 + i2) * 256 + c8];
    f32x4 qa = *(const f32x4*)&qbp[(size_t)(b0 + bb) * 256 + c8];
    f32x4 qc = *(const f32x4*)&qbp[(size_t)(b0 + bb) * 256 + c8 + 4];
    float m[8];
#pragma unroll
    for (int e = 0; e < 4; ++e) m[e] = fmaxf(bf2f(u8[e]) + bf2f(v8[e]) + qa[e], 0.f);
#pragma unroll
    for (int e = 0; e < 4; ++e) m[4 + e] = fmaxf(bf2f(u8[4 + e]) + bf2f(v8[4 + e]) + qc[e], 0.f);
    u32x4 o = {cvtpk(m[0], m[1]), cvtpk(m[2], m[3]), cvtpk(m[4], m[5]), cvtpk(m[6], m[7])};
    *(u32x4*)&sH[row * 256 + (c8 ^ ((row & 15) << 3))] = o;
  }
  __syncthreads();

  f32x4 acc[9][2];

  // L1, L2: swapped operands, in-place sH; every wave: all 9 row-tiles x ni=2 cols.
#pragma unroll 1
  for (int L = 0; L < 2; ++L) {
    const short* __restrict__ Wp = L ? Wg3p : Wg2p;
    const float* __restrict__ bp = L ? bg3 : bg2;
#pragma unroll
    for (int ni = 0; ni < 2; ++ni) {
      f32x4 b4 = *(const f32x4*)&bp[(w * 2 + ni) * 16 + quad * 4];
#pragma unroll
      for (int mt = 0; mt < 9; ++mt) acc[mt][ni] = b4;
    }
#pragma unroll 1
    for (int kt = 0; kt < 8; ++kt) {
      short8v wv[2];
#pragma unroll
      for (int ni = 0; ni < 2; ++ni)
        wv[ni] = *(const short8v*)&Wp[(((w * 2 + ni) * 8 + kt) * 64 + lane) * 8];
      __builtin_amdgcn_s_setprio(1);
#pragma unroll
      for (int mt = 0; mt < 9; ++mt) {
        short8v h = *(const short8v*)&sH[(mt * 16 + ll) * 256 + ((kt * 32 + quad * 8) ^ xl)];
#pragma unroll
        for (int ni = 0; ni < 2; ++ni) acc[mt][ni] = mfma16(wv[ni], h, acc[mt][ni]);
      }
      __builtin_amdgcn_s_setprio(0);
    }
    __syncthreads();  // all reads of sH done before in-place overwrite
#pragma unroll
    for (int ni = 0; ni < 2; ++ni) {
      int c0 = (w * 2 + ni) * 16 + quad * 4;
#pragma unroll
      for (int mt = 0; mt < 9; ++mt) {
        int row = mt * 16 + ll;
        f32x4 a = acc[mt][ni];
        u32x2 o = {cvtpk(fmaxf(a[0], 0.f), fmaxf(a[1], 0.f)),
                   cvtpk(fmaxf(a[2], 0.f), fmaxf(a[3], 0.f))};
        *(u32x2*)&sH[row * 256 + (c0 ^ ((row & 15) << 3))] = o;
      }
    }
    __syncthreads();
  }

  // L3: original order (lane = 4 rows of one col), bias in acc; pool fused in epilogue.
  {
#pragma unroll
    for (int ni = 0; ni < 2; ++ni) {
      float b = bg4[(w * 2 + ni) * 16 + ll];
#pragma unroll
      for (int mt = 0; mt < 9; ++mt) acc[mt][ni] = f32x4{b, b, b, b};
    }
#pragma unroll 1
    for (int kt = 0; kt < 8; ++kt) {
      short8v wv[2];
#pragma unroll
      for (int ni = 0; ni < 2; ++ni)
        wv[ni] = *(const short8v*)&Wg4p[(((w * 2 + ni) * 8 + kt) * 64 + lane) * 8];
      __builtin_amdgcn_s_setprio(1);
#pragma unroll
      for (int mt = 0; mt < 9; ++mt) {
        short8v a = *(const short8v*)&sH[(mt * 16 + ll) * 256 + ((kt * 32 + quad * 8) ^ xl)];
#pragma unroll
        for (int ni = 0; ni < 2; ++ni) acc[mt][ni] = mfma16(a, wv[ni], acc[mt][ni]);
      }
      __builtin_amdgcn_s_setprio(0);
    }
    // register-only pool. Lane rows: rr = mt*16 + quad*4 (+r) in [0,144); batch = rr/36.
#pragma unroll
    for (int ni = 0; ni < 2; ++ni) {
      int col = (w * 2 + ni) * 16 + ll;
      float s0 = 0.f, s1 = 0.f, s2 = 0.f, s3 = 0.f;
#pragma unroll
      for (int mt = 0; mt < 9; ++mt) {
        int rr = mt * 16 + quad * 4;
        float t = 0.f;
#pragma unroll
        for (int r = 0; r < 4; ++r) t += fmaxf(acc[mt][ni][r], 0.f);
        if (rr < 36) s0 += t;
        else if (rr < 72) s1 += t;
        else if (rr < 108) s2 += t;
        else s3 += t;
      }
      s0 += __shfl_xor(s0, 16, 64); s0 += __shfl_xor(s0, 32, 64);
      s1 += __shfl_xor(s1, 16, 64); s1 += __shfl_xor(s1, 32, 64);
      s2 += __shfl_xor(s2, 16, 64); s2 += __shfl_xor(s2, 32, 64);
      s3 += __shfl_xor(s3, 16, 64); s3 += __shfl_xor(s3, 32, 64);
      if (quad == 0) {
        g_g[(size_t)(b0 + 0) * 256 + col] = s0;
        g_g[(size_t)(b0 + 1) * 256 + col] = s1;
        g_g[(size_t)(b0 + 2) * 256 + col] = s2;
        g_g[(size_t)(b0 + 3) * 256 + col] = s3;
      }
    }
  }
}

// ---------- head helper: MTx16 rows x 256 @ 256x256 + bias + relu, LDS->LDS ----------
template<int MT>
__device__ __forceinline__ void gemmMx256(const short* sInp, short* sOut,
    const short* __restrict__ Wp, const float* __restrict__ bias,
    int w, int lane, int quad, int ll, int xl) {
  f32x4 acc[MT][4] = {};
#pragma unroll 1
  for (int kt = 0; kt < 8; ++kt) {
    short8v b[4];
#pragma unroll
    for (int ni = 0; ni < 4; ++ni)
      b[ni] = *(const short8v*)&Wp[(((w * 4 + ni) * 8 + kt) * 64 + lane) * 8];
#pragma unroll
    for (int mt = 0; mt < MT; ++mt) {
      short8v a = *(const short8v*)&sInp[(mt * 16 + ll) * 256 + ((kt * 32 + quad * 8) ^ xl)];
#pragma unroll
      for (int ni = 0; ni < 4; ++ni) acc[mt][ni] = mfma16(a, b[ni], acc[mt][ni]);
    }
  }
#pragma unroll
  for (int ni = 0; ni < 4; ++ni) {
    int col = (w * 4 + ni) * 16 + ll;
    float bv = bias[col];
#pragma unroll
    for (int mt = 0; mt < MT; ++mt)
#pragma unroll
      for (int r = 0; r < 4; ++r) {
        int row = mt * 16 + quad * 4 + r;
        sOut[swz256(row, col)] = f2bf(fmaxf(acc[mt][ni][r] + bv, 0.f));
      }
  }
}

// ---------- head (v13 form): 32 batches/block, 512 blocks ----------
// Round-14 lesson: head is WEIGHT-STREAM-bound (520 KB/block from L2 regardless
// of batch count). Batches/block = weight-reuse factor; the 16-batch split
// doubled weight traffic (266->532 MB) and cost ~8us. Keep 32/block.
__launch_bounds__(256, 4)
__global__ void head_kernel(const float* __restrict__ g_g,
    const short* __restrict__ Wfp, const float* __restrict__ bf_,
    const short* __restrict__ Wo1p, const float* __restrict__ bo1,
    const short* __restrict__ Wo2p, const float* __restrict__ bo2,
    float* __restrict__ outp) {
  __shared__ __align__(16) short sA[32 * 256];
  __shared__ __align__(16) short sB[32 * 256];
  __shared__ float sL[32 * 16];
  const int tid = threadIdx.x;
  const int lane = tid & 63, w = tid >> 6, quad = lane >> 4, ll = lane & 15;
  const int xl = ll << 3;
  const int b0 = blockIdx.x * 32;

#pragma unroll 1
  for (int it = 0; it < 8; ++it) {
    int vi = it * 256 + tid;
    int row = vi >> 6, c4 = (vi & 63) * 4;
    f32x4 gv = *(const f32x4*)&g_g[(size_t)(b0 + row) * 256 + c4];
    short4v o;
#pragma unroll
    for (int e = 0; e < 4; ++e) o[e] = f2bf(gv[e]);
    *(short4v*)&sA[row * 256 + (c4 ^ ((row & 15) << 3))] = o;
  }
  __syncthreads();
  gemmMx256<2>(sA, sB, Wfp, bf_, w, lane, quad, ll, xl);
  __syncthreads();
  gemmMx256<2>(sB, sA, Wo1p, bo1, w, lane, quad, ll, xl);
  __syncthreads();
  if (w < 2) {
    f32x4 acc = {};
#pragma unroll 1
    for (int kt = 0; kt < 8; ++kt) {
      short8v b = *(const short8v*)&Wo2p[(kt * 64 + lane) * 8];
      short8v a = *(const short8v*)&sA[(w * 16 + ll) * 256 + ((kt * 32 + quad * 8) ^ xl)];
      acc = mfma16(a, b, acc);
    }
#pragma unroll
    for (int r = 0; r < 4; ++r) {
      int row = w * 16 + quad * 4 + r;
      sL[row * 16 + ll] = acc[r] + ((ll < 10) ? bo2[ll] : 0.f);
    }
  }
  __syncthreads();
  if (tid < 32) {
    float m = -1e30f;
#pragma unroll
    for (int c = 0; c < 10; ++c) m = fmaxf(m, sL[tid * 16 + c]);
    float s = 0.f;
#pragma unroll
    for (int c = 0; c < 10; ++c) s += expf(sL[tid * 16 + c] - m);
    float ls = logf(s) + m;
#pragma unroll
    for (int c = 0; c < 10; ++c) outp[(size_t)(b0 + tid) * 10 + c] = sL[tid * 16 + c] - ls;
  }
}

extern "C" void kernel_launch(void* const* d_in, const int* in_sizes, int n_in,
                              void* d_out, int out_size, void* d_ws, size_t ws_size,
                              hipStream_t stream) {
  const float* tabs = (const float*)d_in[0];
  const float* qst  = (const float*)d_in[1];
  const float* Wi1 = (const float*)d_in[2];  const float* bi1 = (const float*)d_in[3];
  const float* Wi2 = (const float*)d_in[4];  const float* bi2 = (const float*)d_in[5];
  const float* Wi3 = (const float*)d_in[6];  const float* bi3 = (const float*)d_in[7];
  const float* Wg1 = (const float*)d_in[8];  const float* bg1 = (const float*)d_in[9];
  const float* Wg2 = (const float*)d_in[10]; const float* bg2 = (const float*)d_in[11];
  const float* Wg3 = (const float*)d_in[12]; const float* bg3 = (const float*)d_in[13];
  const float* Wg4 = (const float*)d_in[14]; const float* bg4 = (const float*)d_in[15];
  const float* Wf  = (const float*)d_in[16]; const float* bf_ = (const float*)d_in[17];
  const float* Wo1 = (const float*)d_in[18]; const float* bo1 = (const float*)d_in[19];
  const float* Wo2 = (const float*)d_in[20]; const float* bo2 = (const float*)d_in[21];
  float* outp = (float*)d_out;
  (void)in_sizes; (void)n_in; (void)out_size; (void)ws_size;

  char* ws = (char*)d_ws;
  size_t off = 0;
  auto alloc = [&](size_t bytes) { void* p = ws + off; off += (bytes + 255) & ~(size_t)255; return p; };
  const size_t BN = 16384ull * 6;
  short* u_g = (short*)alloc(BN * 256 * 2);
  short* v_g = (short*)alloc(BN * 256 * 2);
  float* qb  = (float*)alloc(16384ull * 256 * 4);
  float* g_g = (float*)alloc(16384ull * 256 * 4);
  short* Wi1p = (short*)alloc(16 * 1 * 64 * 8 * 2);
  short* Wi2p = (short*)alloc(8 * 8 * 64 * 8 * 2);
  short* Wi3p = (short*)alloc(8 * 4 * 64 * 8 * 2);
  short* Wap  = (short*)alloc(16 * 4 * 64 * 8 * 2);
  short* Wbp  = (short*)alloc(16 * 4 * 64 * 8 * 2);
  short* Wg2p = (short*)alloc(16 * 8 * 64 * 8 * 2);
  short* Wg3p = (short*)alloc(16 * 8 * 64 * 8 * 2);
  short* Wg4p = (short*)alloc(16 * 8 * 64 * 8 * 2);
  short* Wfp  = (short*)alloc(16 * 8 * 64 * 8 * 2);
  short* Wo1p = (short*)alloc(16 * 8 * 64 * 8 * 2);
  short* Wo2p = (short*)alloc(1 * 8 * 64 * 8 * 2);

  PPArgs pa;
  int tb = 0, nd = 0;
  auto add = [&](const float* src, short* dst, int Ks, int Ns, int KT, int NT) {
    pa.d[nd++] = PPDesc{src, dst, Ks, Ns, KT, NT, tb};
    tb += KT * NT;
  };
  add(Wi1, Wi1p, 10, 256, 1, 16);
  add(Wi2, Wi2p, 256, 128, 8, 8);
  add(Wi3, Wi3p, 128, 100, 4, 8);
  add(Wg1,             Wap, 100, 256, 4, 16);
  add(Wg1 + 100 * 256, Wbp, 100, 256, 4, 16);
  add(Wg2, Wg2p, 256, 256, 8, 16);
  add(Wg3, Wg3p, 256, 256, 8, 16);
  add(Wg4, Wg4p, 256, 256, 8, 16);
  add(Wf,  Wfp,  256, 256, 8, 16);
  add(Wo1, Wo1p, 256, 256, 8, 16);
  add(Wo2, Wo2p, 256, 10, 8, 1);
  pa.n_desc = nd;
  pa.total_tiles = tb;
  pa.pp_blocks = (tb * 64 + 255) / 256;
  // merged prepack + qb: one launch, qb runs concurrent with weight prepack
  prepack_all<<<pa.pp_blocks + 512, 256, 0, stream>>>(pa, qst, Wg1, bg1, qb);

  enc_kernel<<<1536, 256, 0, stream>>>(tabs, bi1, bi2, bi3, Wi1p, Wi2p, Wi3p, Wap, Wbp, u_g, v_g);
  pair_kernel<<<4096, 512, 0, stream>>>(u_g, v_g, qb, Wg2p, Wg3p, Wg4p, bg2, bg3, bg4, g_g);
  head_kernel<<<512, 256, 0, stream>>>(g_g, Wfp, bf_, Wo1p, bo1, Wo2p, bo2, outp);
}

// Round 15
// 365.311 us; speedup vs baseline: 1.0304x; 1.0153x over previous
//
#include <hip/hip_runtime.h>
#include <hip/hip_bf16.h>
#include <stdint.h>

// ---------- types ----------
typedef __attribute__((ext_vector_type(8))) __bf16 bf16x8;
typedef __attribute__((ext_vector_type(8))) short short8v;
typedef __attribute__((ext_vector_type(4))) short short4v;
typedef __attribute__((ext_vector_type(4))) float f32x4;
typedef __attribute__((ext_vector_type(2))) uint32_t u32x2;
typedef __attribute__((ext_vector_type(4))) uint32_t u32x4;

__device__ __forceinline__ float bf2f(short u) {
  return __builtin_bit_cast(float, (uint32_t)((uint32_t)(uint16_t)u << 16));
}
__device__ __forceinline__ short f2bf(float f) {
  uint32_t x = __builtin_bit_cast(uint32_t, f);
  x += 0x7FFFu + ((x >> 16) & 1u);
  return (short)(x >> 16);
}
// packed f32->2xbf16 (RNE, identical rounding to f2bf). low16 = lo, high16 = hi.
__device__ __forceinline__ uint32_t cvtpk(float lo, float hi) {
  uint32_t r;
  asm("v_cvt_pk_bf16_f32 %0, %1, %2" : "=v"(r) : "v"(lo), "v"(hi));
  return r;
}
__device__ __forceinline__ f32x4 mfma16(short8v a, short8v b, f32x4 c) {
  return __builtin_amdgcn_mfma_f32_16x16x32_bf16(
      __builtin_bit_cast(bf16x8, a), __builtin_bit_cast(bf16x8, b), c, 0, 0, 0);
}
// XOR-swizzled LDS address (shorts), 16-slot window (conflict-free, round-6).
__device__ __forceinline__ int swz256(int row, int col) {
  return row * 256 + (col ^ ((row & 15) << 3));
}
__device__ __forceinline__ int swz128(int row, int col) {
  return row * 128 + (col ^ ((row & 15) << 3));
}

// ---------- merged prepack + qb: ONE launch ----------
// blocks [0, pp_blocks): weight prepack. blocks [pp_blocks, +512): qb.
struct PPDesc { const float* src; short* dst; int Ks, Ns, KT, NT, tile_base; };
struct PPArgs { PPDesc d[11]; int n_desc; int total_tiles; int pp_blocks; };

__global__ void prepack_all(PPArgs args, const float* __restrict__ qst,
                            const float* __restrict__ Wg1raw,
                            const float* __restrict__ bg1, float* __restrict__ qb) {
  if ((int)blockIdx.x >= args.pp_blocks) {
    // ---- qb path (32 batches/block) ----
    int c = threadIdx.x;
    int b0 = ((int)blockIdx.x - args.pp_blocks) * 32;
    float wcol[11];
#pragma unroll
    for (int k = 0; k < 11; ++k) wcol[k] = Wg1raw[(200 + k) * 256 + c];
    float bias = bg1[c];
#pragma unroll 1
    for (int bb = 0; bb < 32; ++bb) {
      int b = b0 + bb;
      float acc = bias;
#pragma unroll
      for (int k = 0; k < 11; ++k) acc += qst[b * 11 + k] * wcol[k];
      qb[b * 256 + c] = acc;
    }
    return;
  }
  // ---- prepack path ----
  int idx = blockIdx.x * 256 + threadIdx.x;
  int tile = idx >> 6;
  if (tile >= args.total_tiles) return;
  int lane = idx & 63;
  int e = 0;
  while (e + 1 < args.n_desc && args.d[e + 1].tile_base <= tile) ++e;
  const PPDesc D = args.d[e];
  int t = tile - D.tile_base;
  int kt = t % D.KT, nt = t / D.KT;
  int n = nt * 16 + (lane & 15);
  int kbase = kt * 32 + ((lane >> 4) * 8);
  short8v o;
#pragma unroll
  for (int j = 0; j < 8; ++j) {
    int k = kbase + j;
    o[j] = f2bf((k < D.Ks && n < D.Ns) ? D.src[k * D.Ns + n] : 0.f);
  }
  *(short8v*)&D.dst[((size_t)t * 64 + lane) * 8] = o;
}

// ---------- encoder: tabs[64 rows x 10] -> x -> uq=bf16(x@Wa + qb), v=bf16(x@Wb) ----------
// v16: qb folded into u at enc time (f32 add, single RNE pack). Removes 16 MB
// qb reads + 8 f32 adds/chunk from pair's h1. Round-3 lesson applied: L4 keeps
// the FULL acc[4][4] / 16-tile structure (cols 0..255 all covered; v3's failure
// was acc[2][4] covering only cols 0..127, not the fold itself). qb rows staged
// in sQ (aliases dead sH2, <=12 KB); barrier between L4a MFMA and epilogue.
__launch_bounds__(256, 3)
__global__ void enc_kernel(const float* __restrict__ tabs,
    const float* __restrict__ bi1, const float* __restrict__ bi2, const float* __restrict__ bi3,
    const short* __restrict__ Wi1p, const short* __restrict__ Wi2p, const short* __restrict__ Wi3p,
    const short* __restrict__ Wap, const short* __restrict__ Wbp,
    const float* __restrict__ qb,
    short* __restrict__ uq_g, short* __restrict__ v_g) {
  __shared__ __align__(16) short sIn[64 * 32];   // K padded 10->32
  __shared__ __align__(16) short sH1[64 * 256];  // swizzled; sX aliases this after L2
  __shared__ __align__(16) short sH2[64 * 128];  // swizzled; sQ aliases after L3
  short* sX = sH1;                               // reuse (stride 128, swizzled)
  const int tid = threadIdx.x;
  const int lane = tid & 63, w = tid >> 6, quad = lane >> 4, ll = lane & 15;
  const int xl = ll << 3;
  const int obj0 = blockIdx.x * 64;
  const int b_lo = obj0 / 6;

  for (int idx = tid; idx < 64 * 32; idx += 256) {
    int r = idx >> 5, k = idx & 31;
    float v = (k < 10) ? tabs[(obj0 + r) * 10 + k] : 0.f;
    sIn[idx] = f2bf(v);
  }
  __syncthreads();

  // L1: relu(in @ Wi1 + bi1)  K=32(pad), N=256  (swapped; acc[mi=W-tile][nt=row-tile])
  {
    f32x4 acc[4][4];
#pragma unroll
    for (int mi = 0; mi < 4; ++mi) {
      f32x4 b4 = *(const f32x4*)&bi1[(w * 4 + mi) * 16 + quad * 4];
#pragma unroll
      for (int nt = 0; nt < 4; ++nt) acc[mi][nt] = b4;
    }
    short8v wv[4];
#pragma unroll
    for (int mi = 0; mi < 4; ++mi)
      wv[mi] = *(const short8v*)&Wi1p[((w * 4 + mi) * 64 + lane) * 8];
#pragma unroll
    for (int nt = 0; nt < 4; ++nt) {
      short8v a = *(const short8v*)&sIn[(nt * 16 + ll) * 32 + quad * 8];
#pragma unroll
      for (int mi = 0; mi < 4; ++mi) acc[mi][nt] = mfma16(wv[mi], a, acc[mi][nt]);
    }
#pragma unroll
    for (int mi = 0; mi < 4; ++mi) {
      int c0 = (w * 4 + mi) * 16 + quad * 4;
#pragma unroll
      for (int nt = 0; nt < 4; ++nt) {
        int row = nt * 16 + ll;
        f32x4 a = acc[mi][nt];
        u32x2 o = {cvtpk(fmaxf(a[0], 0.f), fmaxf(a[1], 0.f)),
                   cvtpk(fmaxf(a[2], 0.f), fmaxf(a[3], 0.f))};
        *(u32x2*)&sH1[row * 256 + (c0 ^ ((row & 15) << 3))] = o;
      }
    }
  }
  __syncthreads();

  // L2: relu(h1 @ Wi2 + bi2)  K=256, N=128  (swapped)
  {
    f32x4 acc[2][4];
#pragma unroll
    for (int mi = 0; mi < 2; ++mi) {
      f32x4 b4 = *(const f32x4*)&bi2[(w * 2 + mi) * 16 + quad * 4];
#pragma unroll
      for (int nt = 0; nt < 4; ++nt) acc[mi][nt] = b4;
    }
#pragma unroll 1
    for (int kt = 0; kt < 8; ++kt) {
      short8v wv[2];
#pragma unroll
      for (int mi = 0; mi < 2; ++mi)
        wv[mi] = *(const short8v*)&Wi2p[(((w * 2 + mi) * 8 + kt) * 64 + lane) * 8];
#pragma unroll
      for (int nt = 0; nt < 4; ++nt) {
        short8v a = *(const short8v*)&sH1[(nt * 16 + ll) * 256 + ((kt * 32 + quad * 8) ^ xl)];
#pragma unroll
        for (int mi = 0; mi < 2; ++mi) acc[mi][nt] = mfma16(wv[mi], a, acc[mi][nt]);
      }
    }
    __syncthreads();   // sH1 reads done (sX will overwrite it after L3)
#pragma unroll
    for (int mi = 0; mi < 2; ++mi) {
      int c0 = (w * 2 + mi) * 16 + quad * 4;
#pragma unroll
      for (int nt = 0; nt < 4; ++nt) {
        int row = nt * 16 + ll;
        f32x4 a = acc[mi][nt];
        u32x2 o = {cvtpk(fmaxf(a[0], 0.f), fmaxf(a[1], 0.f)),
                   cvtpk(fmaxf(a[2], 0.f), fmaxf(a[3], 0.f))};
        *(u32x2*)&sH2[row * 128 + (c0 ^ ((row & 15) << 3))] = o;
      }
    }
  }
  __syncthreads();

  // L3: x = h2 @ Wi3 + bi3 (NO relu)  K=128, N=128(pad, cols>=100 zero) -> sX
  // (swapped: lane = 4 consecutive cols of one row; whole-vector col<100 mask)
  {
    f32x4 acc[2][4] = {};
#pragma unroll 1
    for (int kt = 0; kt < 4; ++kt) {
      short8v wv[2];
#pragma unroll
      for (int mi = 0; mi < 2; ++mi)
        wv[mi] = *(const short8v*)&Wi3p[(((w * 2 + mi) * 4 + kt) * 64 + lane) * 8];
#pragma unroll
      for (int nt = 0; nt < 4; ++nt) {
        short8v a = *(const short8v*)&sH2[(nt * 16 + ll) * 128 + ((kt * 32 + quad * 8) ^ xl)];
#pragma unroll
        for (int mi = 0; mi < 2; ++mi) acc[mi][nt] = mfma16(wv[mi], a, acc[mi][nt]);
      }
    }
#pragma unroll
    for (int mi = 0; mi < 2; ++mi) {
      int c0 = (w * 2 + mi) * 16 + quad * 4;
      bool live = (c0 < 100);                       // covers c0..c0+3 (100%4==0)
      f32x4 b4 = live ? *(const f32x4*)&bi3[c0] : f32x4{0.f, 0.f, 0.f, 0.f};
#pragma unroll
      for (int nt = 0; nt < 4; ++nt) {
        int row = nt * 16 + ll;
        f32x4 a = acc[mi][nt];
        u32x2 o;
        if (live) {
          o = u32x2{cvtpk(a[0] + b4[0], a[1] + b4[1]),
                    cvtpk(a[2] + b4[2], a[3] + b4[3])};
        } else {
          o = u32x2{0u, 0u};
        }
        *(u32x2*)&sX[row * 128 + (c0 ^ ((row & 15) << 3))] = o;
      }
    }
  }
  __syncthreads();   // sX ready; sH2 dead -> stage qb rows into sQ

  // stage qb rows for this block (<=12 rows x 256 f32 = 12 KB, aliases sH2 16 KB)
  {
    float* sQ = (float*)sH2;
    int nb = (obj0 + 63) / 6 - b_lo + 1;
#pragma unroll 1
    for (int i = tid; i < nb * 256; i += 256)
      sQ[i] = qb[(size_t)(b_lo + (i >> 8)) * 256 + (i & 255)];
  }

  // L4: uq = bf16(x @ Wa + qb) ; v = bf16(x @ Wb)
  // (swapped, FULL 16 W-tiles: (w*4+mi) covers cols 0..255)
#pragma unroll 1
  for (int pass = 0; pass < 2; ++pass) {
    const short* Wp = pass ? Wbp : Wap;
    f32x4 acc[4][4] = {};
#pragma unroll 1
    for (int kt = 0; kt < 4; ++kt) {
      short8v wv[4];
#pragma unroll
      for (int mi = 0; mi < 4; ++mi)
        wv[mi] = *(const short8v*)&Wp[(((w * 4 + mi) * 4 + kt) * 64 + lane) * 8];
#pragma unroll
      for (int nt = 0; nt < 4; ++nt) {
        short8v xb = *(const short8v*)&sX[(nt * 16 + ll) * 128 + ((kt * 32 + quad * 8) ^ xl)];
#pragma unroll
        for (int mi = 0; mi < 4; ++mi) acc[mi][nt] = mfma16(wv[mi], xb, acc[mi][nt]);
      }
    }
    if (pass == 0) {
      __syncthreads();   // sQ writes visible (staged above, hidden under MFMA)
      const float* sQ = (const float*)sH2;
#pragma unroll
      for (int mi = 0; mi < 4; ++mi) {
        int c0 = (w * 4 + mi) * 16 + quad * 4;
#pragma unroll
        for (int nt = 0; nt < 4; ++nt) {
          int obj = obj0 + nt * 16 + ll;
          f32x4 qv = *(const f32x4*)&sQ[(obj / 6 - b_lo) * 256 + c0];
          f32x4 a = acc[mi][nt];
          u32x2 o = {cvtpk(a[0] + qv[0], a[1] + qv[1]),
                     cvtpk(a[2] + qv[2], a[3] + qv[3])};
          *(u32x2*)&uq_g[(size_t)obj * 256 + c0] = o;
        }
      }
    } else {
#pragma unroll
      for (int mi = 0; mi < 4; ++mi) {
        int c0 = (w * 4 + mi) * 16 + quad * 4;
#pragma unroll
        for (int nt = 0; nt < 4; ++nt) {
          int obj = obj0 + nt * 16 + ll;
          f32x4 a = acc[mi][nt];
          u32x2 o = {cvtpk(a[0], a[1]), cvtpk(a[2], a[3])};
          *(u32x2*)&v_g[(size_t)obj * 256 + c0] = o;
        }
      }
    }
  }
}

// ---------- pair MLP v16: v13 structure, h1 = relu(uq + v) (qb pre-folded) ----------
// Sentinels: VGPR 56, LDS 73728, WRITE_SIZE exactly 16384 KB; FETCH ~43 MB (was 59).
__launch_bounds__(512, 4)
__global__ void pair_kernel(const short* __restrict__ uq_g, const short* __restrict__ v_g,
    const short* __restrict__ Wg2p, const short* __restrict__ Wg3p, const short* __restrict__ Wg4p,
    const float* __restrict__ bg2, const float* __restrict__ bg3, const float* __restrict__ bg4,
    float* __restrict__ g_g) {
  __shared__ __align__(16) short sH[144 * 256];  // 73728 B, swizzled, no pad rows
  const int tid = threadIdx.x;
  const int lane = tid & 63, w = tid >> 6, quad = lane >> 4, ll = lane & 15;
  const int xl = ll << 3;
  const int b0 = blockIdx.x * 4;

  // h1 = relu(uq[j] + v[i]); row = bb*36 + i*6 + j in [0,144); 4608 = 9x512 chunks.
#pragma unroll 1
  for (int it = 0; it < 9; ++it) {
    int vi = it * 512 + tid;
    int row = vi >> 5, c8 = (vi & 31) * 8;
    int bb = row / 36, p = row - bb * 36;
    int i2 = p / 6, j2 = p - i2 * 6;
    short8v u8 = *(const short8v*)&uq_g[(size_t)((b0 + bb) * 6 + j2) * 256 + c8];
    short8v v8 = *(const short8v*)&v_g[(size_t)((b0 + bb) * 6 + i2) * 256 + c8];
    float m[8];
#pragma unroll
    for (int e = 0; e < 8; ++e) m[e] = fmaxf(bf2f(u8[e]) + bf2f(v8[e]), 0.f);
    u32x4 o = {cvtpk(m[0], m[1]), cvtpk(m[2], m[3]), cvtpk(m[4], m[5]), cvtpk(m[6], m[7])};
    *(u32x4*)&sH[row * 256 + (c8 ^ ((row & 15) << 3))] = o;
  }
  __syncthreads();

  f32x4 acc[9][2];

  // L1, L2: swapped operands, in-place sH; every wave: all 9 row-tiles x ni=2 cols.
#pragma unroll 1
  for (int L = 0; L < 2; ++L) {
    const short* __restrict__ Wp = L ? Wg3p : Wg2p;
    const float* __restrict__ bp = L ? bg3 : bg2;
#pragma unroll
    for (int ni = 0; ni < 2; ++ni) {
      f32x4 b4 = *(const f32x4*)&bp[(w * 2 + ni) * 16 + quad * 4];
#pragma unroll
      for (int mt = 0; mt < 9; ++mt) acc[mt][ni] = b4;
    }
#pragma unroll 1
    for (int kt = 0; kt < 8; ++kt) {
      short8v wv[2];
#pragma unroll
      for (int ni = 0; ni < 2; ++ni)
        wv[ni] = *(const short8v*)&Wp[(((w * 2 + ni) * 8 + kt) * 64 + lane) * 8];
      __builtin_amdgcn_s_setprio(1);
#pragma unroll
      for (int mt = 0; mt < 9; ++mt) {
        short8v h = *(const short8v*)&sH[(mt * 16 + ll) * 256 + ((kt * 32 + quad * 8) ^ xl)];
#pragma unroll
        for (int ni = 0; ni < 2; ++ni) acc[mt][ni] = mfma16(wv[ni], h, acc[mt][ni]);
      }
      __builtin_amdgcn_s_setprio(0);
    }
    __syncthreads();  // all reads of sH done before in-place overwrite
#pragma unroll
    for (int ni = 0; ni < 2; ++ni) {
      int c0 = (w * 2 + ni) * 16 + quad * 4;
#pragma unroll
      for (int mt = 0; mt < 9; ++mt) {
        int row = mt * 16 + ll;
        f32x4 a = acc[mt][ni];
        u32x2 o = {cvtpk(fmaxf(a[0], 0.f), fmaxf(a[1], 0.f)),
                   cvtpk(fmaxf(a[2], 0.f), fmaxf(a[3], 0.f))};
        *(u32x2*)&sH[row * 256 + (c0 ^ ((row & 15) << 3))] = o;
      }
    }
    __syncthreads();
  }

  // L3: original order (lane = 4 rows of one col), bias in acc; pool fused in epilogue.
  {
#pragma unroll
    for (int ni = 0; ni < 2; ++ni) {
      float b = bg4[(w * 2 + ni) * 16 + ll];
#pragma unroll
      for (int mt = 0; mt < 9; ++mt) acc[mt][ni] = f32x4{b, b, b, b};
    }
#pragma unroll 1
    for (int kt = 0; kt < 8; ++kt) {
      short8v wv[2];
#pragma unroll
      for (int ni = 0; ni < 2; ++ni)
        wv[ni] = *(const short8v*)&Wg4p[(((w * 2 + ni) * 8 + kt) * 64 + lane) * 8];
      __builtin_amdgcn_s_setprio(1);
#pragma unroll
      for (int mt = 0; mt < 9; ++mt) {
        short8v a = *(const short8v*)&sH[(mt * 16 + ll) * 256 + ((kt * 32 + quad * 8) ^ xl)];
#pragma unroll
        for (int ni = 0; ni < 2; ++ni) acc[mt][ni] = mfma16(a, wv[ni], acc[mt][ni]);
      }
      __builtin_amdgcn_s_setprio(0);
    }
    // register-only pool. Lane rows: rr = mt*16 + quad*4 (+r) in [0,144); batch = rr/36.
#pragma unroll
    for (int ni = 0; ni < 2; ++ni) {
      int col = (w * 2 + ni) * 16 + ll;
      float s0 = 0.f, s1 = 0.f, s2 = 0.f, s3 = 0.f;
#pragma unroll
      for (int mt = 0; mt < 9; ++mt) {
        int rr = mt * 16 + quad * 4;
        float t = 0.f;
#pragma unroll
        for (int r = 0; r < 4; ++r) t += fmaxf(acc[mt][ni][r], 0.f);
        if (rr < 36) s0 += t;
        else if (rr < 72) s1 += t;
        else if (rr < 108) s2 += t;
        else s3 += t;
      }
      s0 += __shfl_xor(s0, 16, 64); s0 += __shfl_xor(s0, 32, 64);
      s1 += __shfl_xor(s1, 16, 64); s1 += __shfl_xor(s1, 32, 64);
      s2 += __shfl_xor(s2, 16, 64); s2 += __shfl_xor(s2, 32, 64);
      s3 += __shfl_xor(s3, 16, 64); s3 += __shfl_xor(s3, 32, 64);
      if (quad == 0) {
        g_g[(size_t)(b0 + 0) * 256 + col] = s0;
        g_g[(size_t)(b0 + 1) * 256 + col] = s1;
        g_g[(size_t)(b0 + 2) * 256 + col] = s2;
        g_g[(size_t)(b0 + 3) * 256 + col] = s3;
      }
    }
  }
}

// ---------- head helper: MTx16 rows x 256 @ 256x256 + bias + relu, LDS->LDS ----------
template<int MT>
__device__ __forceinline__ void gemmMx256(const short* sInp, short* sOut,
    const short* __restrict__ Wp, const float* __restrict__ bias,
    int w, int lane, int quad, int ll, int xl) {
  f32x4 acc[MT][4] = {};
#pragma unroll 1
  for (int kt = 0; kt < 8; ++kt) {
    short8v b[4];
#pragma unroll
    for (int ni = 0; ni < 4; ++ni)
      b[ni] = *(const short8v*)&Wp[(((w * 4 + ni) * 8 + kt) * 64 + lane) * 8];
#pragma unroll
    for (int mt = 0; mt < MT; ++mt) {
      short8v a = *(const short8v*)&sInp[(mt * 16 + ll) * 256 + ((kt * 32 + quad * 8) ^ xl)];
#pragma unroll
      for (int ni = 0; ni < 4; ++ni) acc[mt][ni] = mfma16(a, b[ni], acc[mt][ni]);
    }
  }
#pragma unroll
  for (int ni = 0; ni < 4; ++ni) {
    int col = (w * 4 + ni) * 16 + ll;
    float bv = bias[col];
#pragma unroll
    for (int mt = 0; mt < MT; ++mt)
#pragma unroll
      for (int r = 0; r < 4; ++r) {
        int row = mt * 16 + quad * 4 + r;
        sOut[swz256(row, col)] = f2bf(fmaxf(acc[mt][ni][r] + bv, 0.f));
      }
  }
}

// ---------- head (32 batches/block, 512 blocks — weight-stream-bound, keep reuse) ----------
__launch_bounds__(256, 4)
__global__ void head_kernel(const float* __restrict__ g_g,
    const short* __restrict__ Wfp, const float* __restrict__ bf_,
    const short* __restrict__ Wo1p, const float* __restrict__ bo1,
    const short* __restrict__ Wo2p, const float* __restrict__ bo2,
    float* __restrict__ outp) {
  __shared__ __align__(16) short sA[32 * 256];
  __shared__ __align__(16) short sB[32 * 256];
  __shared__ float sL[32 * 16];
  const int tid = threadIdx.x;
  const int lane = tid & 63, w = tid >> 6, quad = lane >> 4, ll = lane & 15;
  const int xl = ll << 3;
  const int b0 = blockIdx.x * 32;

#pragma unroll 1
  for (int it = 0; it < 8; ++it) {
    int vi = it * 256 + tid;
    int row = vi >> 6, c4 = (vi & 63) * 4;
    f32x4 gv = *(const f32x4*)&g_g[(size_t)(b0 + row) * 256 + c4];
    short4v o;
#pragma unroll
    for (int e = 0; e < 4; ++e) o[e] = f2bf(gv[e]);
    *(short4v*)&sA[row * 256 + (c4 ^ ((row & 15) << 3))] = o;
  }
  __syncthreads();
  gemmMx256<2>(sA, sB, Wfp, bf_, w, lane, quad, ll, xl);
  __syncthreads();
  gemmMx256<2>(sB, sA, Wo1p, bo1, w, lane, quad, ll, xl);
  __syncthreads();
  if (w < 2) {
    f32x4 acc = {};
#pragma unroll 1
    for (int kt = 0; kt < 8; ++kt) {
      short8v b = *(const short8v*)&Wo2p[(kt * 64 + lane) * 8];
      short8v a = *(const short8v*)&sA[(w * 16 + ll) * 256 + ((kt * 32 + quad * 8) ^ xl)];
      acc = mfma16(a, b, acc);
    }
#pragma unroll
    for (int r = 0; r < 4; ++r) {
      int row = w * 16 + quad * 4 + r;
      sL[row * 16 + ll] = acc[r] + ((ll < 10) ? bo2[ll] : 0.f);
    }
  }
  __syncthreads();
  if (tid < 32) {
    float m = -1e30f;
#pragma unroll
    for (int c = 0; c < 10; ++c) m = fmaxf(m, sL[tid * 16 + c]);
    float s = 0.f;
#pragma unroll
    for (int c = 0; c < 10; ++c) s += expf(sL[tid * 16 + c] - m);
    float ls = logf(s) + m;
#pragma unroll
    for (int c = 0; c < 10; ++c) outp[(size_t)(b0 + tid) * 10 + c] = sL[tid * 16 + c] - ls;
  }
}

extern "C" void kernel_launch(void* const* d_in, const int* in_sizes, int n_in,
                              void* d_out, int out_size, void* d_ws, size_t ws_size,
                              hipStream_t stream) {
  const float* tabs = (const float*)d_in[0];
  const float* qst  = (const float*)d_in[1];
  const float* Wi1 = (const float*)d_in[2];  const float* bi1 = (const float*)d_in[3];
  const float* Wi2 = (const float*)d_in[4];  const float* bi2 = (const float*)d_in[5];
  const float* Wi3 = (const float*)d_in[6];  const float* bi3 = (const float*)d_in[7];
  const float* Wg1 = (const float*)d_in[8];  const float* bg1 = (const float*)d_in[9];
  const float* Wg2 = (const float*)d_in[10]; const float* bg2 = (const float*)d_in[11];
  const float* Wg3 = (const float*)d_in[12]; const float* bg3 = (const float*)d_in[13];
  const float* Wg4 = (const float*)d_in[14]; const float* bg4 = (const float*)d_in[15];
  const float* Wf  = (const float*)d_in[16]; const float* bf_ = (const float*)d_in[17];
  const float* Wo1 = (const float*)d_in[18]; const float* bo1 = (const float*)d_in[19];
  const float* Wo2 = (const float*)d_in[20]; const float* bo2 = (const float*)d_in[21];
  float* outp = (float*)d_out;
  (void)in_sizes; (void)n_in; (void)out_size; (void)ws_size;

  char* ws = (char*)d_ws;
  size_t off = 0;
  auto alloc = [&](size_t bytes) { void* p = ws + off; off += (bytes + 255) & ~(size_t)255; return p; };
  const size_t BN = 16384ull * 6;
  short* uq_g = (short*)alloc(BN * 256 * 2);   // bf16(u + qb)
  short* v_g  = (short*)alloc(BN * 256 * 2);
  float* qb   = (float*)alloc(16384ull * 256 * 4);
  float* g_g  = (float*)alloc(16384ull * 256 * 4);
  short* Wi1p = (short*)alloc(16 * 1 * 64 * 8 * 2);
  short* Wi2p = (short*)alloc(8 * 8 * 64 * 8 * 2);
  short* Wi3p = (short*)alloc(8 * 4 * 64 * 8 * 2);
  short* Wap  = (short*)alloc(16 * 4 * 64 * 8 * 2);
  short* Wbp  = (short*)alloc(16 * 4 * 64 * 8 * 2);
  short* Wg2p = (short*)alloc(16 * 8 * 64 * 8 * 2);
  short* Wg3p = (short*)alloc(16 * 8 * 64 * 8 * 2);
  short* Wg4p = (short*)alloc(16 * 8 * 64 * 8 * 2);
  short* Wfp  = (short*)alloc(16 * 8 * 64 * 8 * 2);
  short* Wo1p = (short*)alloc(16 * 8 * 64 * 8 * 2);
  short* Wo2p = (short*)alloc(1 * 8 * 64 * 8 * 2);

  PPArgs pa;
  int tb = 0, nd = 0;
  auto add = [&](const float* src, short* dst, int Ks, int Ns, int KT, int NT) {
    pa.d[nd++] = PPDesc{src, dst, Ks, Ns, KT, NT, tb};
    tb += KT * NT;
  };
  add(Wi1, Wi1p, 10, 256, 1, 16);
  add(Wi2, Wi2p, 256, 128, 8, 8);
  add(Wi3, Wi3p, 128, 100, 4, 8);
  add(Wg1,             Wap, 100, 256, 4, 16);
  add(Wg1 + 100 * 256, Wbp, 100, 256, 4, 16);
  add(Wg2, Wg2p, 256, 256, 8, 16);
  add(Wg3, Wg3p, 256, 256, 8, 16);
  add(Wg4, Wg4p, 256, 256, 8, 16);
  add(Wf,  Wfp,  256, 256, 8, 16);
  add(Wo1, Wo1p, 256, 256, 8, 16);
  add(Wo2, Wo2p, 256, 10, 8, 1);
  pa.n_desc = nd;
  pa.total_tiles = tb;
  pa.pp_blocks = (tb * 64 + 255) / 256;
  // merged prepack + qb: one launch, qb runs concurrent with weight prepack
  prepack_all<<<pa.pp_blocks + 512, 256, 0, stream>>>(pa, qst, Wg1, bg1, qb);

  enc_kernel<<<1536, 256, 0, stream>>>(tabs, bi1, bi2, bi3, Wi1p, Wi2p, Wi3p, Wap, Wbp,
                                       qb, uq_g, v_g);
  pair_kernel<<<4096, 512, 0, stream>>>(uq_g, v_g, Wg2p, Wg3p, Wg4p, bg2, bg3, bg4, g_g);
  head_kernel<<<512, 256, 0, stream>>>(g_g, Wfp, bf_, Wo1p, bo1, Wo2p, bo2, outp);
}

// Round 16
// 364.735 us; speedup vs baseline: 1.0320x; 1.0016x over previous
//
#include <hip/hip_runtime.h>
#include <hip/hip_bf16.h>
#include <stdint.h>

// ---------- types ----------
typedef __attribute__((ext_vector_type(8))) __bf16 bf16x8;
typedef __attribute__((ext_vector_type(8))) short short8v;
typedef __attribute__((ext_vector_type(4))) short short4v;
typedef __attribute__((ext_vector_type(4))) float f32x4;
typedef __attribute__((ext_vector_type(2))) uint32_t u32x2;
typedef __attribute__((ext_vector_type(4))) uint32_t u32x4;

__device__ __forceinline__ float bf2f(short u) {
  return __builtin_bit_cast(float, (uint32_t)((uint32_t)(uint16_t)u << 16));
}
__device__ __forceinline__ short f2bf(float f) {
  uint32_t x = __builtin_bit_cast(uint32_t, f);
  x += 0x7FFFu + ((x >> 16) & 1u);
  return (short)(x >> 16);
}
// packed f32->2xbf16 (RNE, identical rounding to f2bf). low16 = lo, high16 = hi.
__device__ __forceinline__ uint32_t cvtpk(float lo, float hi) {
  uint32_t r;
  asm("v_cvt_pk_bf16_f32 %0, %1, %2" : "=v"(r) : "v"(lo), "v"(hi));
  return r;
}
__device__ __forceinline__ f32x4 mfma16(short8v a, short8v b, f32x4 c) {
  return __builtin_amdgcn_mfma_f32_16x16x32_bf16(
      __builtin_bit_cast(bf16x8, a), __builtin_bit_cast(bf16x8, b), c, 0, 0, 0);
}
// XOR-swizzled LDS address (shorts), 16-slot window (conflict-free, round-6).
__device__ __forceinline__ int swz256(int row, int col) {
  return row * 256 + (col ^ ((row & 15) << 3));
}
__device__ __forceinline__ int swz128(int row, int col) {
  return row * 128 + (col ^ ((row & 15) << 3));
}

// ---------- merged prepack + qb: ONE launch ----------
// blocks [0, pp_blocks): weight prepack. blocks [pp_blocks, +512): qb.
struct PPDesc { const float* src; short* dst; int Ks, Ns, KT, NT, tile_base; };
struct PPArgs { PPDesc d[11]; int n_desc; int total_tiles; int pp_blocks; };

__global__ void prepack_all(PPArgs args, const float* __restrict__ qst,
                            const float* __restrict__ Wg1raw,
                            const float* __restrict__ bg1, float* __restrict__ qb) {
  if ((int)blockIdx.x >= args.pp_blocks) {
    // ---- qb path (32 batches/block) ----
    int c = threadIdx.x;
    int b0 = ((int)blockIdx.x - args.pp_blocks) * 32;
    float wcol[11];
#pragma unroll
    for (int k = 0; k < 11; ++k) wcol[k] = Wg1raw[(200 + k) * 256 + c];
    float bias = bg1[c];
#pragma unroll 1
    for (int bb = 0; bb < 32; ++bb) {
      int b = b0 + bb;
      float acc = bias;
#pragma unroll
      for (int k = 0; k < 11; ++k) acc += qst[b * 11 + k] * wcol[k];
      qb[b * 256 + c] = acc;
    }
    return;
  }
  // ---- prepack path ----
  int idx = blockIdx.x * 256 + threadIdx.x;
  int tile = idx >> 6;
  if (tile >= args.total_tiles) return;
  int lane = idx & 63;
  int e = 0;
  while (e + 1 < args.n_desc && args.d[e + 1].tile_base <= tile) ++e;
  const PPDesc D = args.d[e];
  int t = tile - D.tile_base;
  int kt = t % D.KT, nt = t / D.KT;
  int n = nt * 16 + (lane & 15);
  int kbase = kt * 32 + ((lane >> 4) * 8);
  short8v o;
#pragma unroll
  for (int j = 0; j < 8; ++j) {
    int k = kbase + j;
    o[j] = f2bf((k < D.Ks && n < D.Ns) ? D.src[k * D.Ns + n] : 0.f);
  }
  *(short8v*)&D.dst[((size_t)t * 64 + lane) * 8] = o;
}

// ---------- encoder: tabs[64 rows x 10] -> x -> uq=bf16(x@Wa + qb), v=bf16(x@Wb) ----------
// qb folded into u at enc time (f32 add, single RNE pack) -> pair h1 needs no qb.
// L4 keeps FULL acc[4][4] / 16-tile structure (cols 0..255 all covered).
__launch_bounds__(256, 3)
__global__ void enc_kernel(const float* __restrict__ tabs,
    const float* __restrict__ bi1, const float* __restrict__ bi2, const float* __restrict__ bi3,
    const short* __restrict__ Wi1p, const short* __restrict__ Wi2p, const short* __restrict__ Wi3p,
    const short* __restrict__ Wap, const short* __restrict__ Wbp,
    const float* __restrict__ qb,
    short* __restrict__ uq_g, short* __restrict__ v_g) {
  __shared__ __align__(16) short sIn[64 * 32];   // K padded 10->32
  __shared__ __align__(16) short sH1[64 * 256];  // swizzled; sX aliases this after L2
  __shared__ __align__(16) short sH2[64 * 128];  // swizzled; sQ aliases after L3
  short* sX = sH1;                               // reuse (stride 128, swizzled)
  const int tid = threadIdx.x;
  const int lane = tid & 63, w = tid >> 6, quad = lane >> 4, ll = lane & 15;
  const int xl = ll << 3;
  const int obj0 = blockIdx.x * 64;
  const int b_lo = obj0 / 6;

  for (int idx = tid; idx < 64 * 32; idx += 256) {
    int r = idx >> 5, k = idx & 31;
    float v = (k < 10) ? tabs[(obj0 + r) * 10 + k] : 0.f;
    sIn[idx] = f2bf(v);
  }
  __syncthreads();

  // L1: relu(in @ Wi1 + bi1)  K=32(pad), N=256  (swapped; acc[mi=W-tile][nt=row-tile])
  {
    f32x4 acc[4][4];
#pragma unroll
    for (int mi = 0; mi < 4; ++mi) {
      f32x4 b4 = *(const f32x4*)&bi1[(w * 4 + mi) * 16 + quad * 4];
#pragma unroll
      for (int nt = 0; nt < 4; ++nt) acc[mi][nt] = b4;
    }
    short8v wv[4];
#pragma unroll
    for (int mi = 0; mi < 4; ++mi)
      wv[mi] = *(const short8v*)&Wi1p[((w * 4 + mi) * 64 + lane) * 8];
#pragma unroll
    for (int nt = 0; nt < 4; ++nt) {
      short8v a = *(const short8v*)&sIn[(nt * 16 + ll) * 32 + quad * 8];
#pragma unroll
      for (int mi = 0; mi < 4; ++mi) acc[mi][nt] = mfma16(wv[mi], a, acc[mi][nt]);
    }
#pragma unroll
    for (int mi = 0; mi < 4; ++mi) {
      int c0 = (w * 4 + mi) * 16 + quad * 4;
#pragma unroll
      for (int nt = 0; nt < 4; ++nt) {
        int row = nt * 16 + ll;
        f32x4 a = acc[mi][nt];
        u32x2 o = {cvtpk(fmaxf(a[0], 0.f), fmaxf(a[1], 0.f)),
                   cvtpk(fmaxf(a[2], 0.f), fmaxf(a[3], 0.f))};
        *(u32x2*)&sH1[row * 256 + (c0 ^ ((row & 15) << 3))] = o;
      }
    }
  }
  __syncthreads();

  // L2: relu(h1 @ Wi2 + bi2)  K=256, N=128  (swapped)
  {
    f32x4 acc[2][4];
#pragma unroll
    for (int mi = 0; mi < 2; ++mi) {
      f32x4 b4 = *(const f32x4*)&bi2[(w * 2 + mi) * 16 + quad * 4];
#pragma unroll
      for (int nt = 0; nt < 4; ++nt) acc[mi][nt] = b4;
    }
#pragma unroll 1
    for (int kt = 0; kt < 8; ++kt) {
      short8v wv[2];
#pragma unroll
      for (int mi = 0; mi < 2; ++mi)
        wv[mi] = *(const short8v*)&Wi2p[(((w * 2 + mi) * 8 + kt) * 64 + lane) * 8];
#pragma unroll
      for (int nt = 0; nt < 4; ++nt) {
        short8v a = *(const short8v*)&sH1[(nt * 16 + ll) * 256 + ((kt * 32 + quad * 8) ^ xl)];
#pragma unroll
        for (int mi = 0; mi < 2; ++mi) acc[mi][nt] = mfma16(wv[mi], a, acc[mi][nt]);
      }
    }
    __syncthreads();   // sH1 reads done (sX will overwrite it after L3)
#pragma unroll
    for (int mi = 0; mi < 2; ++mi) {
      int c0 = (w * 2 + mi) * 16 + quad * 4;
#pragma unroll
      for (int nt = 0; nt < 4; ++nt) {
        int row = nt * 16 + ll;
        f32x4 a = acc[mi][nt];
        u32x2 o = {cvtpk(fmaxf(a[0], 0.f), fmaxf(a[1], 0.f)),
                   cvtpk(fmaxf(a[2], 0.f), fmaxf(a[3], 0.f))};
        *(u32x2*)&sH2[row * 128 + (c0 ^ ((row & 15) << 3))] = o;
      }
    }
  }
  __syncthreads();

  // L3: x = h2 @ Wi3 + bi3 (NO relu)  K=128, N=128(pad, cols>=100 zero) -> sX
  // (swapped: lane = 4 consecutive cols of one row; whole-vector col<100 mask)
  {
    f32x4 acc[2][4] = {};
#pragma unroll 1
    for (int kt = 0; kt < 4; ++kt) {
      short8v wv[2];
#pragma unroll
      for (int mi = 0; mi < 2; ++mi)
        wv[mi] = *(const short8v*)&Wi3p[(((w * 2 + mi) * 4 + kt) * 64 + lane) * 8];
#pragma unroll
      for (int nt = 0; nt < 4; ++nt) {
        short8v a = *(const short8v*)&sH2[(nt * 16 + ll) * 128 + ((kt * 32 + quad * 8) ^ xl)];
#pragma unroll
        for (int mi = 0; mi < 2; ++mi) acc[mi][nt] = mfma16(wv[mi], a, acc[mi][nt]);
      }
    }
#pragma unroll
    for (int mi = 0; mi < 2; ++mi) {
      int c0 = (w * 2 + mi) * 16 + quad * 4;
      bool live = (c0 < 100);                       // covers c0..c0+3 (100%4==0)
      f32x4 b4 = live ? *(const f32x4*)&bi3[c0] : f32x4{0.f, 0.f, 0.f, 0.f};
#pragma unroll
      for (int nt = 0; nt < 4; ++nt) {
        int row = nt * 16 + ll;
        f32x4 a = acc[mi][nt];
        u32x2 o;
        if (live) {
          o = u32x2{cvtpk(a[0] + b4[0], a[1] + b4[1]),
                    cvtpk(a[2] + b4[2], a[3] + b4[3])};
        } else {
          o = u32x2{0u, 0u};
        }
        *(u32x2*)&sX[row * 128 + (c0 ^ ((row & 15) << 3))] = o;
      }
    }
  }
  __syncthreads();   // sX ready; sH2 dead -> stage qb rows into sQ

  // stage qb rows for this block (<=12 rows x 256 f32 = 12 KB, aliases sH2 16 KB)
  {
    float* sQ = (float*)sH2;
    int nb = (obj0 + 63) / 6 - b_lo + 1;
#pragma unroll 1
    for (int i = tid; i < nb * 256; i += 256)
      sQ[i] = qb[(size_t)(b_lo + (i >> 8)) * 256 + (i & 255)];
  }

  // L4: uq = bf16(x @ Wa + qb) ; v = bf16(x @ Wb)
  // (swapped, FULL 16 W-tiles: (w*4+mi) covers cols 0..255)
#pragma unroll 1
  for (int pass = 0; pass < 2; ++pass) {
    const short* Wp = pass ? Wbp : Wap;
    f32x4 acc[4][4] = {};
#pragma unroll 1
    for (int kt = 0; kt < 4; ++kt) {
      short8v wv[4];
#pragma unroll
      for (int mi = 0; mi < 4; ++mi)
        wv[mi] = *(const short8v*)&Wp[(((w * 4 + mi) * 4 + kt) * 64 + lane) * 8];
#pragma unroll
      for (int nt = 0; nt < 4; ++nt) {
        short8v xb = *(const short8v*)&sX[(nt * 16 + ll) * 128 + ((kt * 32 + quad * 8) ^ xl)];
#pragma unroll
        for (int mi = 0; mi < 4; ++mi) acc[mi][nt] = mfma16(wv[mi], xb, acc[mi][nt]);
      }
    }
    if (pass == 0) {
      __syncthreads();   // sQ writes visible (staged above, hidden under MFMA)
      const float* sQ = (const float*)sH2;
#pragma unroll
      for (int mi = 0; mi < 4; ++mi) {
        int c0 = (w * 4 + mi) * 16 + quad * 4;
#pragma unroll
        for (int nt = 0; nt < 4; ++nt) {
          int obj = obj0 + nt * 16 + ll;
          f32x4 qv = *(const f32x4*)&sQ[(obj / 6 - b_lo) * 256 + c0];
          f32x4 a = acc[mi][nt];
          u32x2 o = {cvtpk(a[0] + qv[0], a[1] + qv[1]),
                     cvtpk(a[2] + qv[2], a[3] + qv[3])};
          *(u32x2*)&uq_g[(size_t)obj * 256 + c0] = o;
        }
      }
    } else {
#pragma unroll
      for (int mi = 0; mi < 4; ++mi) {
        int c0 = (w * 4 + mi) * 16 + quad * 4;
#pragma unroll
        for (int nt = 0; nt < 4; ++nt) {
          int obj = obj0 + nt * 16 + ll;
          f32x4 a = acc[mi][nt];
          u32x2 o = {cvtpk(a[0], a[1]), cvtpk(a[2], a[3])};
          *(u32x2*)&v_g[(size_t)obj * 256 + c0] = o;
        }
      }
    }
  }
}

// ---------- pair MLP v17: v16 + h1 unroll 2 (ISOLATED load pipelining) ----------
// v9's unroll-3 failure was the bundled +70-reg MM staging (spill); during h1 the
// acc array is not yet live, so unroll 2 costs only ~+25 transient regs (56->~80).
// Sentinels: VGPR <= 88, LDS 73728, WRITE_SIZE exactly 16384 KB, FETCH ~50.7 MB.
__launch_bounds__(512, 4)
__global__ void pair_kernel(const short* __restrict__ uq_g, const short* __restrict__ v_g,
    const short* __restrict__ Wg2p, const short* __restrict__ Wg3p, const short* __restrict__ Wg4p,
    const float* __restrict__ bg2, const float* __restrict__ bg3, const float* __restrict__ bg4,
    float* __restrict__ g_g) {
  __shared__ __align__(16) short sH[144 * 256];  // 73728 B, swizzled, no pad rows
  const int tid = threadIdx.x;
  const int lane = tid & 63, w = tid >> 6, quad = lane >> 4, ll = lane & 15;
  const int xl = ll << 3;
  const int b0 = blockIdx.x * 4;

  // h1 = relu(uq[j] + v[i]); row = bb*36 + i*6 + j in [0,144); 4608 = 9x512 chunks.
  // unroll 2: two iterations' global loads in flight (acc not yet live; no spill).
#pragma unroll 2
  for (int it = 0; it < 9; ++it) {
    int vi = it * 512 + tid;
    int row = vi >> 5, c8 = (vi & 31) * 8;
    int bb = row / 36, p = row - bb * 36;
    int i2 = p / 6, j2 = p - i2 * 6;
    short8v u8 = *(const short8v*)&uq_g[(size_t)((b0 + bb) * 6 + j2) * 256 + c8];
    short8v v8 = *(const short8v*)&v_g[(size_t)((b0 + bb) * 6 + i2) * 256 + c8];
    float m[8];
#pragma unroll
    for (int e = 0; e < 8; ++e) m[e] = fmaxf(bf2f(u8[e]) + bf2f(v8[e]), 0.f);
    u32x4 o = {cvtpk(m[0], m[1]), cvtpk(m[2], m[3]), cvtpk(m[4], m[5]), cvtpk(m[6], m[7])};
    *(u32x4*)&sH[row * 256 + (c8 ^ ((row & 15) << 3))] = o;
  }
  __syncthreads();

  f32x4 acc[9][2];

  // L1, L2: swapped operands, in-place sH; every wave: all 9 row-tiles x ni=2 cols.
#pragma unroll 1
  for (int L = 0; L < 2; ++L) {
    const short* __restrict__ Wp = L ? Wg3p : Wg2p;
    const float* __restrict__ bp = L ? bg3 : bg2;
#pragma unroll
    for (int ni = 0; ni < 2; ++ni) {
      f32x4 b4 = *(const f32x4*)&bp[(w * 2 + ni) * 16 + quad * 4];
#pragma unroll
      for (int mt = 0; mt < 9; ++mt) acc[mt][ni] = b4;
    }
#pragma unroll 1
    for (int kt = 0; kt < 8; ++kt) {
      short8v wv[2];
#pragma unroll
      for (int ni = 0; ni < 2; ++ni)
        wv[ni] = *(const short8v*)&Wp[(((w * 2 + ni) * 8 + kt) * 64 + lane) * 8];
      __builtin_amdgcn_s_setprio(1);
#pragma unroll
      for (int mt = 0; mt < 9; ++mt) {
        short8v h = *(const short8v*)&sH[(mt * 16 + ll) * 256 + ((kt * 32 + quad * 8) ^ xl)];
#pragma unroll
        for (int ni = 0; ni < 2; ++ni) acc[mt][ni] = mfma16(wv[ni], h, acc[mt][ni]);
      }
      __builtin_amdgcn_s_setprio(0);
    }
    __syncthreads();  // all reads of sH done before in-place overwrite
#pragma unroll
    for (int ni = 0; ni < 2; ++ni) {
      int c0 = (w * 2 + ni) * 16 + quad * 4;
#pragma unroll
      for (int mt = 0; mt < 9; ++mt) {
        int row = mt * 16 + ll;
        f32x4 a = acc[mt][ni];
        u32x2 o = {cvtpk(fmaxf(a[0], 0.f), fmaxf(a[1], 0.f)),
                   cvtpk(fmaxf(a[2], 0.f), fmaxf(a[3], 0.f))};
        *(u32x2*)&sH[row * 256 + (c0 ^ ((row & 15) << 3))] = o;
      }
    }
    __syncthreads();
  }

  // L3: original order (lane = 4 rows of one col), bias in acc; pool fused in epilogue.
  {
#pragma unroll
    for (int ni = 0; ni < 2; ++ni) {
      float b = bg4[(w * 2 + ni) * 16 + ll];
#pragma unroll
      for (int mt = 0; mt < 9; ++mt) acc[mt][ni] = f32x4{b, b, b, b};
    }
#pragma unroll 1
    for (int kt = 0; kt < 8; ++kt) {
      short8v wv[2];
#pragma unroll
      for (int ni = 0; ni < 2; ++ni)
        wv[ni] = *(const short8v*)&Wg4p[(((w * 2 + ni) * 8 + kt) * 64 + lane) * 8];
      __builtin_amdgcn_s_setprio(1);
#pragma unroll
      for (int mt = 0; mt < 9; ++mt) {
        short8v a = *(const short8v*)&sH[(mt * 16 + ll) * 256 + ((kt * 32 + quad * 8) ^ xl)];
#pragma unroll
        for (int ni = 0; ni < 2; ++ni) acc[mt][ni] = mfma16(a, wv[ni], acc[mt][ni]);
      }
      __builtin_amdgcn_s_setprio(0);
    }
    // register-only pool. Lane rows: rr = mt*16 + quad*4 (+r) in [0,144); batch = rr/36.
#pragma unroll
    for (int ni = 0; ni < 2; ++ni) {
      int col = (w * 2 + ni) * 16 + ll;
      float s0 = 0.f, s1 = 0.f, s2 = 0.f, s3 = 0.f;
#pragma unroll
      for (int mt = 0; mt < 9; ++mt) {
        int rr = mt * 16 + quad * 4;
        float t = 0.f;
#pragma unroll
        for (int r = 0; r < 4; ++r) t += fmaxf(acc[mt][ni][r], 0.f);
        if (rr < 36) s0 += t;
        else if (rr < 72) s1 += t;
        else if (rr < 108) s2 += t;
        else s3 += t;
      }
      s0 += __shfl_xor(s0, 16, 64); s0 += __shfl_xor(s0, 32, 64);
      s1 += __shfl_xor(s1, 16, 64); s1 += __shfl_xor(s1, 32, 64);
      s2 += __shfl_xor(s2, 16, 64); s2 += __shfl_xor(s2, 32, 64);
      s3 += __shfl_xor(s3, 16, 64); s3 += __shfl_xor(s3, 32, 64);
      if (quad == 0) {
        g_g[(size_t)(b0 + 0) * 256 + col] = s0;
        g_g[(size_t)(b0 + 1) * 256 + col] = s1;
        g_g[(size_t)(b0 + 2) * 256 + col] = s2;
        g_g[(size_t)(b0 + 3) * 256 + col] = s3;
      }
    }
  }
}

// ---------- head helper: MTx16 rows x 256 @ 256x256 + bias + relu, LDS->LDS ----------
template<int MT>
__device__ __forceinline__ void gemmMx256(const short* sInp, short* sOut,
    const short* __restrict__ Wp, const float* __restrict__ bias,
    int w, int lane, int quad, int ll, int xl) {
  f32x4 acc[MT][4] = {};
#pragma unroll 1
  for (int kt = 0; kt < 8; ++kt) {
    short8v b[4];
#pragma unroll
    for (int ni = 0; ni < 4; ++ni)
      b[ni] = *(const short8v*)&Wp[(((w * 4 + ni) * 8 + kt) * 64 + lane) * 8];
#pragma unroll
    for (int mt = 0; mt < MT; ++mt) {
      short8v a = *(const short8v*)&sInp[(mt * 16 + ll) * 256 + ((kt * 32 + quad * 8) ^ xl)];
#pragma unroll
      for (int ni = 0; ni < 4; ++ni) acc[mt][ni] = mfma16(a, b[ni], acc[mt][ni]);
    }
  }
#pragma unroll
  for (int ni = 0; ni < 4; ++ni) {
    int col = (w * 4 + ni) * 16 + ll;
    float bv = bias[col];
#pragma unroll
    for (int mt = 0; mt < MT; ++mt)
#pragma unroll
      for (int r = 0; r < 4; ++r) {
        int row = mt * 16 + quad * 4 + r;
        sOut[swz256(row, col)] = f2bf(fmaxf(acc[mt][ni][r] + bv, 0.f));
      }
  }
}

// ---------- head (32 batches/block, 512 blocks — weight-stream-bound, keep reuse) ----------
__launch_bounds__(256, 4)
__global__ void head_kernel(const float* __restrict__ g_g,
    const short* __restrict__ Wfp, const float* __restrict__ bf_,
    const short* __restrict__ Wo1p, const float* __restrict__ bo1,
    const short* __restrict__ Wo2p, const float* __restrict__ bo2,
    float* __restrict__ outp) {
  __shared__ __align__(16) short sA[32 * 256];
  __shared__ __align__(16) short sB[32 * 256];
  __shared__ float sL[32 * 16];
  const int tid = threadIdx.x;
  const int lane = tid & 63, w = tid >> 6, quad = lane >> 4, ll = lane & 15;
  const int xl = ll << 3;
  const int b0 = blockIdx.x * 32;

#pragma unroll 1
  for (int it = 0; it < 8; ++it) {
    int vi = it * 256 + tid;
    int row = vi >> 6, c4 = (vi & 63) * 4;
    f32x4 gv = *(const f32x4*)&g_g[(size_t)(b0 + row) * 256 + c4];
    short4v o;
#pragma unroll
    for (int e = 0; e < 4; ++e) o[e] = f2bf(gv[e]);
    *(short4v*)&sA[row * 256 + (c4 ^ ((row & 15) << 3))] = o;
  }
  __syncthreads();
  gemmMx256<2>(sA, sB, Wfp, bf_, w, lane, quad, ll, xl);
  __syncthreads();
  gemmMx256<2>(sB, sA, Wo1p, bo1, w, lane, quad, ll, xl);
  __syncthreads();
  if (w < 2) {
    f32x4 acc = {};
#pragma unroll 1
    for (int kt = 0; kt < 8; ++kt) {
      short8v b = *(const short8v*)&Wo2p[(kt * 64 + lane) * 8];
      short8v a = *(const short8v*)&sA[(w * 16 + ll) * 256 + ((kt * 32 + quad * 8) ^ xl)];
      acc = mfma16(a, b, acc);
    }
#pragma unroll
    for (int r = 0; r < 4; ++r) {
      int row = w * 16 + quad * 4 + r;
      sL[row * 16 + ll] = acc[r] + ((ll < 10) ? bo2[ll] : 0.f);
    }
  }
  __syncthreads();
  if (tid < 32) {
    float m = -1e30f;
#pragma unroll
    for (int c = 0; c < 10; ++c) m = fmaxf(m, sL[tid * 16 + c]);
    float s = 0.f;
#pragma unroll
    for (int c = 0; c < 10; ++c) s += expf(sL[tid * 16 + c] - m);
    float ls = logf(s) + m;
#pragma unroll
    for (int c = 0; c < 10; ++c) outp[(size_t)(b0 + tid) * 10 + c] = sL[tid * 16 + c] - ls;
  }
}

extern "C" void kernel_launch(void* const* d_in, const int* in_sizes, int n_in,
                              void* d_out, int out_size, void* d_ws, size_t ws_size,
                              hipStream_t stream) {
  const float* tabs = (const float*)d_in[0];
  const float* qst  = (const float*)d_in[1];
  const float* Wi1 = (const float*)d_in[2];  const float* bi1 = (const float*)d_in[3];
  const float* Wi2 = (const float*)d_in[4];  const float* bi2 = (const float*)d_in[5];
  const float* Wi3 = (const float*)d_in[6];  const float* bi3 = (const float*)d_in[7];
  const float* Wg1 = (const float*)d_in[8];  const float* bg1 = (const float*)d_in[9];
  const float* Wg2 = (const float*)d_in[10]; const float* bg2 = (const float*)d_in[11];
  const float* Wg3 = (const float*)d_in[12]; const float* bg3 = (const float*)d_in[13];
  const float* Wg4 = (const float*)d_in[14]; const float* bg4 = (const float*)d_in[15];
  const float* Wf  = (const float*)d_in[16]; const float* bf_ = (const float*)d_in[17];
  const float* Wo1 = (const float*)d_in[18]; const float* bo1 = (const float*)d_in[19];
  const float* Wo2 = (const float*)d_in[20]; const float* bo2 = (const float*)d_in[21];
  float* outp = (float*)d_out;
  (void)in_sizes; (void)n_in; (void)out_size; (void)ws_size;

  char* ws = (char*)d_ws;
  size_t off = 0;
  auto alloc = [&](size_t bytes) { void* p = ws + off; off += (bytes + 255) & ~(size_t)255; return p; };
  const size_t BN = 16384ull * 6;
  short* uq_g = (short*)alloc(BN * 256 * 2);   // bf16(u + qb)
  short* v_g  = (short*)alloc(BN * 256 * 2);
  float* qb   = (float*)alloc(16384ull * 256 * 4);
  float* g_g  = (float*)alloc(16384ull * 256 * 4);
  short* Wi1p = (short*)alloc(16 * 1 * 64 * 8 * 2);
  short* Wi2p = (short*)alloc(8 * 8 * 64 * 8 * 2);
  short* Wi3p = (short*)alloc(8 * 4 * 64 * 8 * 2);
  short* Wap  = (short*)alloc(16 * 4 * 64 * 8 * 2);
  short* Wbp  = (short*)alloc(16 * 4 * 64 * 8 * 2);
  short* Wg2p = (short*)alloc(16 * 8 * 64 * 8 * 2);
  short* Wg3p = (short*)alloc(16 * 8 * 64 * 8 * 2);
  short* Wg4p = (short*)alloc(16 * 8 * 64 * 8 * 2);
  short* Wfp  = (short*)alloc(16 * 8 * 64 * 8 * 2);
  short* Wo1p = (short*)alloc(16 * 8 * 64 * 8 * 2);
  short* Wo2p = (short*)alloc(1 * 8 * 64 * 8 * 2);

  PPArgs pa;
  int tb = 0, nd = 0;
  auto add = [&](const float* src, short* dst, int Ks, int Ns, int KT, int NT) {
    pa.d[nd++] = PPDesc{src, dst, Ks, Ns, KT, NT, tb};
    tb += KT * NT;
  };
  add(Wi1, Wi1p, 10, 256, 1, 16);
  add(Wi2, Wi2p, 256, 128, 8, 8);
  add(Wi3, Wi3p, 128, 100, 4, 8);
  add(Wg1,             Wap, 100, 256, 4, 16);
  add(Wg1 + 100 * 256, Wbp, 100, 256, 4, 16);
  add(Wg2, Wg2p, 256, 256, 8, 16);
  add(Wg3, Wg3p, 256, 256, 8, 16);
  add(Wg4, Wg4p, 256, 256, 8, 16);
  add(Wf,  Wfp,  256, 256, 8, 16);
  add(Wo1, Wo1p, 256, 256, 8, 16);
  add(Wo2, Wo2p, 256, 10, 8, 1);
  pa.n_desc = nd;
  pa.total_tiles = tb;
  pa.pp_blocks = (tb * 64 + 255) / 256;
  // merged prepack + qb: one launch, qb runs concurrent with weight prepack
  prepack_all<<<pa.pp_blocks + 512, 256, 0, stream>>>(pa, qst, Wg1, bg1, qb);

  enc_kernel<<<1536, 256, 0, stream>>>(tabs, bi1, bi2, bi3, Wi1p, Wi2p, Wi3p, Wap, Wbp,
                                       qb, uq_g, v_g);
  pair_kernel<<<4096, 512, 0, stream>>>(uq_g, v_g, Wg2p, Wg3p, Wg4p, bg2, bg3, bg4, g_g);
  head_kernel<<<512, 256, 0, stream>>>(g_g, Wfp, bf_, Wo1p, bo1, Wo2p, bo2, outp);
}

// Round 17
// 358.816 us; speedup vs baseline: 1.0491x; 1.0165x over previous
//
#include <hip/hip_runtime.h>
#include <hip/hip_bf16.h>
#include <stdint.h>

// ---------- types ----------
typedef __attribute__((ext_vector_type(8))) __bf16 bf16x8;
typedef __attribute__((ext_vector_type(8))) short short8v;
typedef __attribute__((ext_vector_type(4))) short short4v;
typedef __attribute__((ext_vector_type(4))) float f32x4;
typedef __attribute__((ext_vector_type(2))) uint32_t u32x2;
typedef __attribute__((ext_vector_type(4))) uint32_t u32x4;

__device__ __forceinline__ float bf2f(short u) {
  return __builtin_bit_cast(float, (uint32_t)((uint32_t)(uint16_t)u << 16));
}
__device__ __forceinline__ short f2bf(float f) {
  uint32_t x = __builtin_bit_cast(uint32_t, f);
  x += 0x7FFFu + ((x >> 16) & 1u);
  return (short)(x >> 16);
}
// packed f32->2xbf16 (RNE, identical rounding to f2bf). low16 = lo, high16 = hi.
__device__ __forceinline__ uint32_t cvtpk(float lo, float hi) {
  uint32_t r;
  asm("v_cvt_pk_bf16_f32 %0, %1, %2" : "=v"(r) : "v"(lo), "v"(hi));
  return r;
}
__device__ __forceinline__ f32x4 mfma16(short8v a, short8v b, f32x4 c) {
  return __builtin_amdgcn_mfma_f32_16x16x32_bf16(
      __builtin_bit_cast(bf16x8, a), __builtin_bit_cast(bf16x8, b), c, 0, 0, 0);
}
// XOR-swizzled LDS address (shorts), 16-slot window (conflict-free, round-6).
__device__ __forceinline__ int swz256(int row, int col) {
  return row * 256 + (col ^ ((row & 15) << 3));
}
__device__ __forceinline__ int swz128(int row, int col) {
  return row * 128 + (col ^ ((row & 15) << 3));
}

// ---------- merged prepack + qb: ONE launch ----------
// blocks [0, pp_blocks): weight prepack. blocks [pp_blocks, +512): qb.
struct PPDesc { const float* src; short* dst; int Ks, Ns, KT, NT, tile_base; };
struct PPArgs { PPDesc d[11]; int n_desc; int total_tiles; int pp_blocks; };

__global__ void prepack_all(PPArgs args, const float* __restrict__ qst,
                            const float* __restrict__ Wg1raw,
                            const float* __restrict__ bg1, float* __restrict__ qb) {
  if ((int)blockIdx.x >= args.pp_blocks) {
    // ---- qb path (32 batches/block) ----
    int c = threadIdx.x;
    int b0 = ((int)blockIdx.x - args.pp_blocks) * 32;
    float wcol[11];
#pragma unroll
    for (int k = 0; k < 11; ++k) wcol[k] = Wg1raw[(200 + k) * 256 + c];
    float bias = bg1[c];
#pragma unroll 1
    for (int bb = 0; bb < 32; ++bb) {
      int b = b0 + bb;
      float acc = bias;
#pragma unroll
      for (int k = 0; k < 11; ++k) acc += qst[b * 11 + k] * wcol[k];
      qb[b * 256 + c] = acc;
    }
    return;
  }
  // ---- prepack path ----
  int idx = blockIdx.x * 256 + threadIdx.x;
  int tile = idx >> 6;
  if (tile >= args.total_tiles) return;
  int lane = idx & 63;
  int e = 0;
  while (e + 1 < args.n_desc && args.d[e + 1].tile_base <= tile) ++e;
  const PPDesc D = args.d[e];
  int t = tile - D.tile_base;
  int kt = t % D.KT, nt = t / D.KT;
  int n = nt * 16 + (lane & 15);
  int kbase = kt * 32 + ((lane >> 4) * 8);
  short8v o;
#pragma unroll
  for (int j = 0; j < 8; ++j) {
    int k = kbase + j;
    o[j] = f2bf((k < D.Ks && n < D.Ns) ? D.src[k * D.Ns + n] : 0.f);
  }
  *(short8v*)&D.dst[((size_t)t * 64 + lane) * 8] = o;
}

// ---------- encoder: tabs[64 rows x 10] -> x -> uq=bf16(x@Wa + qb), v=bf16(x@Wb) ----------
// qb folded into u at enc time (f32 add, single RNE pack) -> pair h1 needs no qb.
// L4 keeps FULL acc[4][4] / 16-tile structure (cols 0..255 all covered).
__launch_bounds__(256, 3)
__global__ void enc_kernel(const float* __restrict__ tabs,
    const float* __restrict__ bi1, const float* __restrict__ bi2, const float* __restrict__ bi3,
    const short* __restrict__ Wi1p, const short* __restrict__ Wi2p, const short* __restrict__ Wi3p,
    const short* __restrict__ Wap, const short* __restrict__ Wbp,
    const float* __restrict__ qb,
    short* __restrict__ uq_g, short* __restrict__ v_g) {
  __shared__ __align__(16) short sIn[64 * 32];   // K padded 10->32
  __shared__ __align__(16) short sH1[64 * 256];  // swizzled; sX aliases this after L2
  __shared__ __align__(16) short sH2[64 * 128];  // swizzled; sQ aliases after L3
  short* sX = sH1;                               // reuse (stride 128, swizzled)
  const int tid = threadIdx.x;
  const int lane = tid & 63, w = tid >> 6, quad = lane >> 4, ll = lane & 15;
  const int xl = ll << 3;
  const int obj0 = blockIdx.x * 64;
  const int b_lo = obj0 / 6;

  for (int idx = tid; idx < 64 * 32; idx += 256) {
    int r = idx >> 5, k = idx & 31;
    float v = (k < 10) ? tabs[(obj0 + r) * 10 + k] : 0.f;
    sIn[idx] = f2bf(v);
  }
  __syncthreads();

  // L1: relu(in @ Wi1 + bi1)  K=32(pad), N=256  (swapped; acc[mi=W-tile][nt=row-tile])
  {
    f32x4 acc[4][4];
#pragma unroll
    for (int mi = 0; mi < 4; ++mi) {
      f32x4 b4 = *(const f32x4*)&bi1[(w * 4 + mi) * 16 + quad * 4];
#pragma unroll
      for (int nt = 0; nt < 4; ++nt) acc[mi][nt] = b4;
    }
    short8v wv[4];
#pragma unroll
    for (int mi = 0; mi < 4; ++mi)
      wv[mi] = *(const short8v*)&Wi1p[((w * 4 + mi) * 64 + lane) * 8];
#pragma unroll
    for (int nt = 0; nt < 4; ++nt) {
      short8v a = *(const short8v*)&sIn[(nt * 16 + ll) * 32 + quad * 8];
#pragma unroll
      for (int mi = 0; mi < 4; ++mi) acc[mi][nt] = mfma16(wv[mi], a, acc[mi][nt]);
    }
#pragma unroll
    for (int mi = 0; mi < 4; ++mi) {
      int c0 = (w * 4 + mi) * 16 + quad * 4;
#pragma unroll
      for (int nt = 0; nt < 4; ++nt) {
        int row = nt * 16 + ll;
        f32x4 a = acc[mi][nt];
        u32x2 o = {cvtpk(fmaxf(a[0], 0.f), fmaxf(a[1], 0.f)),
                   cvtpk(fmaxf(a[2], 0.f), fmaxf(a[3], 0.f))};
        *(u32x2*)&sH1[row * 256 + (c0 ^ ((row & 15) << 3))] = o;
      }
    }
  }
  __syncthreads();

  // L2: relu(h1 @ Wi2 + bi2)  K=256, N=128  (swapped)
  {
    f32x4 acc[2][4];
#pragma unroll
    for (int mi = 0; mi < 2; ++mi) {
      f32x4 b4 = *(const f32x4*)&bi2[(w * 2 + mi) * 16 + quad * 4];
#pragma unroll
      for (int nt = 0; nt < 4; ++nt) acc[mi][nt] = b4;
    }
#pragma unroll 1
    for (int kt = 0; kt < 8; ++kt) {
      short8v wv[2];
#pragma unroll
      for (int mi = 0; mi < 2; ++mi)
        wv[mi] = *(const short8v*)&Wi2p[(((w * 2 + mi) * 8 + kt) * 64 + lane) * 8];
#pragma unroll
      for (int nt = 0; nt < 4; ++nt) {
        short8v a = *(const short8v*)&sH1[(nt * 16 + ll) * 256 + ((kt * 32 + quad * 8) ^ xl)];
#pragma unroll
        for (int mi = 0; mi < 2; ++mi) acc[mi][nt] = mfma16(wv[mi], a, acc[mi][nt]);
      }
    }
    __syncthreads();   // sH1 reads done (sX will overwrite it after L3)
#pragma unroll
    for (int mi = 0; mi < 2; ++mi) {
      int c0 = (w * 2 + mi) * 16 + quad * 4;
#pragma unroll
      for (int nt = 0; nt < 4; ++nt) {
        int row = nt * 16 + ll;
        f32x4 a = acc[mi][nt];
        u32x2 o = {cvtpk(fmaxf(a[0], 0.f), fmaxf(a[1], 0.f)),
                   cvtpk(fmaxf(a[2], 0.f), fmaxf(a[3], 0.f))};
        *(u32x2*)&sH2[row * 128 + (c0 ^ ((row & 15) << 3))] = o;
      }
    }
  }
  __syncthreads();

  // L3: x = h2 @ Wi3 + bi3 (NO relu)  K=128, N=128(pad, cols>=100 zero) -> sX
  // (swapped: lane = 4 consecutive cols of one row; whole-vector col<100 mask)
  {
    f32x4 acc[2][4] = {};
#pragma unroll 1
    for (int kt = 0; kt < 4; ++kt) {
      short8v wv[2];
#pragma unroll
      for (int mi = 0; mi < 2; ++mi)
        wv[mi] = *(const short8v*)&Wi3p[(((w * 2 + mi) * 4 + kt) * 64 + lane) * 8];
#pragma unroll
      for (int nt = 0; nt < 4; ++nt) {
        short8v a = *(const short8v*)&sH2[(nt * 16 + ll) * 128 + ((kt * 32 + quad * 8) ^ xl)];
#pragma unroll
        for (int mi = 0; mi < 2; ++mi) acc[mi][nt] = mfma16(wv[mi], a, acc[mi][nt]);
      }
    }
#pragma unroll
    for (int mi = 0; mi < 2; ++mi) {
      int c0 = (w * 2 + mi) * 16 + quad * 4;
      bool live = (c0 < 100);                       // covers c0..c0+3 (100%4==0)
      f32x4 b4 = live ? *(const f32x4*)&bi3[c0] : f32x4{0.f, 0.f, 0.f, 0.f};
#pragma unroll
      for (int nt = 0; nt < 4; ++nt) {
        int row = nt * 16 + ll;
        f32x4 a = acc[mi][nt];
        u32x2 o;
        if (live) {
          o = u32x2{cvtpk(a[0] + b4[0], a[1] + b4[1]),
                    cvtpk(a[2] + b4[2], a[3] + b4[3])};
        } else {
          o = u32x2{0u, 0u};
        }
        *(u32x2*)&sX[row * 128 + (c0 ^ ((row & 15) << 3))] = o;
      }
    }
  }
  __syncthreads();   // sX ready; sH2 dead -> stage qb rows into sQ

  // stage qb rows for this block (<=12 rows x 256 f32 = 12 KB, aliases sH2 16 KB)
  {
    float* sQ = (float*)sH2;
    int nb = (obj0 + 63) / 6 - b_lo + 1;
#pragma unroll 1
    for (int i = tid; i < nb * 256; i += 256)
      sQ[i] = qb[(size_t)(b_lo + (i >> 8)) * 256 + (i & 255)];
  }

  // L4: uq = bf16(x @ Wa + qb) ; v = bf16(x @ Wb)
  // (swapped, FULL 16 W-tiles: (w*4+mi) covers cols 0..255)
#pragma unroll 1
  for (int pass = 0; pass < 2; ++pass) {
    const short* Wp = pass ? Wbp : Wap;
    f32x4 acc[4][4] = {};
#pragma unroll 1
    for (int kt = 0; kt < 4; ++kt) {
      short8v wv[4];
#pragma unroll
      for (int mi = 0; mi < 4; ++mi)
        wv[mi] = *(const short8v*)&Wp[(((w * 4 + mi) * 4 + kt) * 64 + lane) * 8];
#pragma unroll
      for (int nt = 0; nt < 4; ++nt) {
        short8v xb = *(const short8v*)&sX[(nt * 16 + ll) * 128 + ((kt * 32 + quad * 8) ^ xl)];
#pragma unroll
        for (int mi = 0; mi < 4; ++mi) acc[mi][nt] = mfma16(wv[mi], xb, acc[mi][nt]);
      }
    }
    if (pass == 0) {
      __syncthreads();   // sQ writes visible (staged above, hidden under MFMA)
      const float* sQ = (const float*)sH2;
#pragma unroll
      for (int mi = 0; mi < 4; ++mi) {
        int c0 = (w * 4 + mi) * 16 + quad * 4;
#pragma unroll
        for (int nt = 0; nt < 4; ++nt) {
          int obj = obj0 + nt * 16 + ll;
          f32x4 qv = *(const f32x4*)&sQ[(obj / 6 - b_lo) * 256 + c0];
          f32x4 a = acc[mi][nt];
          u32x2 o = {cvtpk(a[0] + qv[0], a[1] + qv[1]),
                     cvtpk(a[2] + qv[2], a[3] + qv[3])};
          *(u32x2*)&uq_g[(size_t)obj * 256 + c0] = o;
        }
      }
    } else {
#pragma unroll
      for (int mi = 0; mi < 4; ++mi) {
        int c0 = (w * 4 + mi) * 16 + quad * 4;
#pragma unroll
        for (int nt = 0; nt < 4; ++nt) {
          int obj = obj0 + nt * 16 + ll;
          f32x4 a = acc[mi][nt];
          u32x2 o = {cvtpk(a[0], a[1]), cvtpk(a[2], a[3])};
          *(u32x2*)&v_g[(size_t)obj * 256 + c0] = o;
        }
      }
    }
  }
}

// ---------- pair MLP v18: v17 with h1 unroll 3 (same verified mechanism, deeper) ----------
// unroll 2 measured -7.6us (6 loads in flight vs 4 now); 9 = 3x3 exact. Transient
// regs ~+15 vs unroll 2, still well under 128. Sentinels: VGPR <= 80, LDS 73728,
// WRITE_SIZE exactly 16384 KB, FETCH ~50.8 MB, absmax 0.015625.
__launch_bounds__(512, 4)
__global__ void pair_kernel(const short* __restrict__ uq_g, const short* __restrict__ v_g,
    const short* __restrict__ Wg2p, const short* __restrict__ Wg3p, const short* __restrict__ Wg4p,
    const float* __restrict__ bg2, const float* __restrict__ bg3, const float* __restrict__ bg4,
    float* __restrict__ g_g) {
  __shared__ __align__(16) short sH[144 * 256];  // 73728 B, swizzled, no pad rows
  const int tid = threadIdx.x;
  const int lane = tid & 63, w = tid >> 6, quad = lane >> 4, ll = lane & 15;
  const int xl = ll << 3;
  const int b0 = blockIdx.x * 4;

  // h1 = relu(uq[j] + v[i]); row = bb*36 + i*6 + j in [0,144); 4608 = 9x512 chunks.
  // unroll 3: three iterations' global loads in flight (acc not yet live; no spill).
#pragma unroll 3
  for (int it = 0; it < 9; ++it) {
    int vi = it * 512 + tid;
    int row = vi >> 5, c8 = (vi & 31) * 8;
    int bb = row / 36, p = row - bb * 36;
    int i2 = p / 6, j2 = p - i2 * 6;
    short8v u8 = *(const short8v*)&uq_g[(size_t)((b0 + bb) * 6 + j2) * 256 + c8];
    short8v v8 = *(const short8v*)&v_g[(size_t)((b0 + bb) * 6 + i2) * 256 + c8];
    float m[8];
#pragma unroll
    for (int e = 0; e < 8; ++e) m[e] = fmaxf(bf2f(u8[e]) + bf2f(v8[e]), 0.f);
    u32x4 o = {cvtpk(m[0], m[1]), cvtpk(m[2], m[3]), cvtpk(m[4], m[5]), cvtpk(m[6], m[7])};
    *(u32x4*)&sH[row * 256 + (c8 ^ ((row & 15) << 3))] = o;
  }
  __syncthreads();

  f32x4 acc[9][2];

  // L1, L2: swapped operands, in-place sH; every wave: all 9 row-tiles x ni=2 cols.
#pragma unroll 1
  for (int L = 0; L < 2; ++L) {
    const short* __restrict__ Wp = L ? Wg3p : Wg2p;
    const float* __restrict__ bp = L ? bg3 : bg2;
#pragma unroll
    for (int ni = 0; ni < 2; ++ni) {
      f32x4 b4 = *(const f32x4*)&bp[(w * 2 + ni) * 16 + quad * 4];
#pragma unroll
      for (int mt = 0; mt < 9; ++mt) acc[mt][ni] = b4;
    }
#pragma unroll 1
    for (int kt = 0; kt < 8; ++kt) {
      short8v wv[2];
#pragma unroll
      for (int ni = 0; ni < 2; ++ni)
        wv[ni] = *(const short8v*)&Wp[(((w * 2 + ni) * 8 + kt) * 64 + lane) * 8];
      __builtin_amdgcn_s_setprio(1);
#pragma unroll
      for (int mt = 0; mt < 9; ++mt) {
        short8v h = *(const short8v*)&sH[(mt * 16 + ll) * 256 + ((kt * 32 + quad * 8) ^ xl)];
#pragma unroll
        for (int ni = 0; ni < 2; ++ni) acc[mt][ni] = mfma16(wv[ni], h, acc[mt][ni]);
      }
      __builtin_amdgcn_s_setprio(0);
    }
    __syncthreads();  // all reads of sH done before in-place overwrite
#pragma unroll
    for (int ni = 0; ni < 2; ++ni) {
      int c0 = (w * 2 + ni) * 16 + quad * 4;
#pragma unroll
      for (int mt = 0; mt < 9; ++mt) {
        int row = mt * 16 + ll;
        f32x4 a = acc[mt][ni];
        u32x2 o = {cvtpk(fmaxf(a[0], 0.f), fmaxf(a[1], 0.f)),
                   cvtpk(fmaxf(a[2], 0.f), fmaxf(a[3], 0.f))};
        *(u32x2*)&sH[row * 256 + (c0 ^ ((row & 15) << 3))] = o;
      }
    }
    __syncthreads();
  }

  // L3: original order (lane = 4 rows of one col), bias in acc; pool fused in epilogue.
  {
#pragma unroll
    for (int ni = 0; ni < 2; ++ni) {
      float b = bg4[(w * 2 + ni) * 16 + ll];
#pragma unroll
      for (int mt = 0; mt < 9; ++mt) acc[mt][ni] = f32x4{b, b, b, b};
    }
#pragma unroll 1
    for (int kt = 0; kt < 8; ++kt) {
      short8v wv[2];
#pragma unroll
      for (int ni = 0; ni < 2; ++ni)
        wv[ni] = *(const short8v*)&Wg4p[(((w * 2 + ni) * 8 + kt) * 64 + lane) * 8];
      __builtin_amdgcn_s_setprio(1);
#pragma unroll
      for (int mt = 0; mt < 9; ++mt) {
        short8v a = *(const short8v*)&sH[(mt * 16 + ll) * 256 + ((kt * 32 + quad * 8) ^ xl)];
#pragma unroll
        for (int ni = 0; ni < 2; ++ni) acc[mt][ni] = mfma16(a, wv[ni], acc[mt][ni]);
      }
      __builtin_amdgcn_s_setprio(0);
    }
    // register-only pool. Lane rows: rr = mt*16 + quad*4 (+r) in [0,144); batch = rr/36.
#pragma unroll
    for (int ni = 0; ni < 2; ++ni) {
      int col = (w * 2 + ni) * 16 + ll;
      float s0 = 0.f, s1 = 0.f, s2 = 0.f, s3 = 0.f;
#pragma unroll
      for (int mt = 0; mt < 9; ++mt) {
        int rr = mt * 16 + quad * 4;
        float t = 0.f;
#pragma unroll
        for (int r = 0; r < 4; ++r) t += fmaxf(acc[mt][ni][r], 0.f);
        if (rr < 36) s0 += t;
        else if (rr < 72) s1 += t;
        else if (rr < 108) s2 += t;
        else s3 += t;
      }
      s0 += __shfl_xor(s0, 16, 64); s0 += __shfl_xor(s0, 32, 64);
      s1 += __shfl_xor(s1, 16, 64); s1 += __shfl_xor(s1, 32, 64);
      s2 += __shfl_xor(s2, 16, 64); s2 += __shfl_xor(s2, 32, 64);
      s3 += __shfl_xor(s3, 16, 64); s3 += __shfl_xor(s3, 32, 64);
      if (quad == 0) {
        g_g[(size_t)(b0 + 0) * 256 + col] = s0;
        g_g[(size_t)(b0 + 1) * 256 + col] = s1;
        g_g[(size_t)(b0 + 2) * 256 + col] = s2;
        g_g[(size_t)(b0 + 3) * 256 + col] = s3;
      }
    }
  }
}

// ---------- head helper: MTx16 rows x 256 @ 256x256 + bias + relu, LDS->LDS ----------
template<int MT>
__device__ __forceinline__ void gemmMx256(const short* sInp, short* sOut,
    const short* __restrict__ Wp, const float* __restrict__ bias,
    int w, int lane, int quad, int ll, int xl) {
  f32x4 acc[MT][4] = {};
#pragma unroll 1
  for (int kt = 0; kt < 8; ++kt) {
    short8v b[4];
#pragma unroll
    for (int ni = 0; ni < 4; ++ni)
      b[ni] = *(const short8v*)&Wp[(((w * 4 + ni) * 8 + kt) * 64 + lane) * 8];
#pragma unroll
    for (int mt = 0; mt < MT; ++mt) {
      short8v a = *(const short8v*)&sInp[(mt * 16 + ll) * 256 + ((kt * 32 + quad * 8) ^ xl)];
#pragma unroll
      for (int ni = 0; ni < 4; ++ni) acc[mt][ni] = mfma16(a, b[ni], acc[mt][ni]);
    }
  }
#pragma unroll
  for (int ni = 0; ni < 4; ++ni) {
    int col = (w * 4 + ni) * 16 + ll;
    float bv = bias[col];
#pragma unroll
    for (int mt = 0; mt < MT; ++mt)
#pragma unroll
      for (int r = 0; r < 4; ++r) {
        int row = mt * 16 + quad * 4 + r;
        sOut[swz256(row, col)] = f2bf(fmaxf(acc[mt][ni][r] + bv, 0.f));
      }
  }
}

// ---------- head (32 batches/block, 512 blocks — weight-stream-bound, keep reuse) ----------
__launch_bounds__(256, 4)
__global__ void head_kernel(const float* __restrict__ g_g,
    const short* __restrict__ Wfp, const float* __restrict__ bf_,
    const short* __restrict__ Wo1p, const float* __restrict__ bo1,
    const short* __restrict__ Wo2p, const float* __restrict__ bo2,
    float* __restrict__ outp) {
  __shared__ __align__(16) short sA[32 * 256];
  __shared__ __align__(16) short sB[32 * 256];
  __shared__ float sL[32 * 16];
  const int tid = threadIdx.x;
  const int lane = tid & 63, w = tid >> 6, quad = lane >> 4, ll = lane & 15;
  const int xl = ll << 3;
  const int b0 = blockIdx.x * 32;

#pragma unroll 1
  for (int it = 0; it < 8; ++it) {
    int vi = it * 256 + tid;
    int row = vi >> 6, c4 = (vi & 63) * 4;
    f32x4 gv = *(const f32x4*)&g_g[(size_t)(b0 + row) * 256 + c4];
    short4v o;
#pragma unroll
    for (int e = 0; e < 4; ++e) o[e] = f2bf(gv[e]);
    *(short4v*)&sA[row * 256 + (c4 ^ ((row & 15) << 3))] = o;
  }
  __syncthreads();
  gemmMx256<2>(sA, sB, Wfp, bf_, w, lane, quad, ll, xl);
  __syncthreads();
  gemmMx256<2>(sB, sA, Wo1p, bo1, w, lane, quad, ll, xl);
  __syncthreads();
  if (w < 2) {
    f32x4 acc = {};
#pragma unroll 1
    for (int kt = 0; kt < 8; ++kt) {
      short8v b = *(const short8v*)&Wo2p[(kt * 64 + lane) * 8];
      short8v a = *(const short8v*)&sA[(w * 16 + ll) * 256 + ((kt * 32 + quad * 8) ^ xl)];
      acc = mfma16(a, b, acc);
    }
#pragma unroll
    for (int r = 0; r < 4; ++r) {
      int row = w * 16 + quad * 4 + r;
      sL[row * 16 + ll] = acc[r] + ((ll < 10) ? bo2[ll] : 0.f);
    }
  }
  __syncthreads();
  if (tid < 32) {
    float m = -1e30f;
#pragma unroll
    for (int c = 0; c < 10; ++c) m = fmaxf(m, sL[tid * 16 + c]);
    float s = 0.f;
#pragma unroll
    for (int c = 0; c < 10; ++c) s += expf(sL[tid * 16 + c] - m);
    float ls = logf(s) + m;
#pragma unroll
    for (int c = 0; c < 10; ++c) outp[(size_t)(b0 + tid) * 10 + c] = sL[tid * 16 + c] - ls;
  }
}

extern "C" void kernel_launch(void* const* d_in, const int* in_sizes, int n_in,
                              void* d_out, int out_size, void* d_ws, size_t ws_size,
                              hipStream_t stream) {
  const float* tabs = (const float*)d_in[0];
  const float* qst  = (const float*)d_in[1];
  const float* Wi1 = (const float*)d_in[2];  const float* bi1 = (const float*)d_in[3];
  const float* Wi2 = (const float*)d_in[4];  const float* bi2 = (const float*)d_in[5];
  const float* Wi3 = (const float*)d_in[6];  const float* bi3 = (const float*)d_in[7];
  const float* Wg1 = (const float*)d_in[8];  const float* bg1 = (const float*)d_in[9];
  const float* Wg2 = (const float*)d_in[10]; const float* bg2 = (const float*)d_in[11];
  const float* Wg3 = (const float*)d_in[12]; const float* bg3 = (const float*)d_in[13];
  const float* Wg4 = (const float*)d_in[14]; const float* bg4 = (const float*)d_in[15];
  const float* Wf  = (const float*)d_in[16]; const float* bf_ = (const float*)d_in[17];
  const float* Wo1 = (const float*)d_in[18]; const float* bo1 = (const float*)d_in[19];
  const float* Wo2 = (const float*)d_in[20]; const float* bo2 = (const float*)d_in[21];
  float* outp = (float*)d_out;
  (void)in_sizes; (void)n_in; (void)out_size; (void)ws_size;

  char* ws = (char*)d_ws;
  size_t off = 0;
  auto alloc = [&](size_t bytes) { void* p = ws + off; off += (bytes + 255) & ~(size_t)255; return p; };
  const size_t BN = 16384ull * 6;
  short* uq_g = (short*)alloc(BN * 256 * 2);   // bf16(u + qb)
  short* v_g  = (short*)alloc(BN * 256 * 2);
  float* qb   = (float*)alloc(16384ull * 256 * 4);
  float* g_g  = (float*)alloc(16384ull * 256 * 4);
  short* Wi1p = (short*)alloc(16 * 1 * 64 * 8 * 2);
  short* Wi2p = (short*)alloc(8 * 8 * 64 * 8 * 2);
  short* Wi3p = (short*)alloc(8 * 4 * 64 * 8 * 2);
  short* Wap  = (short*)alloc(16 * 4 * 64 * 8 * 2);
  short* Wbp  = (short*)alloc(16 * 4 * 64 * 8 * 2);
  short* Wg2p = (short*)alloc(16 * 8 * 64 * 8 * 2);
  short* Wg3p = (short*)alloc(16 * 8 * 64 * 8 * 2);
  short* Wg4p = (short*)alloc(16 * 8 * 64 * 8 * 2);
  short* Wfp  = (short*)alloc(16 * 8 * 64 * 8 * 2);
  short* Wo1p = (short*)alloc(16 * 8 * 64 * 8 * 2);
  short* Wo2p = (short*)alloc(1 * 8 * 64 * 8 * 2);

  PPArgs pa;
  int tb = 0, nd = 0;
  auto add = [&](const float* src, short* dst, int Ks, int Ns, int KT, int NT) {
    pa.d[nd++] = PPDesc{src, dst, Ks, Ns, KT, NT, tb};
    tb += KT * NT;
  };
  add(Wi1, Wi1p, 10, 256, 1, 16);
  add(Wi2, Wi2p, 256, 128, 8, 8);
  add(Wi3, Wi3p, 128, 100, 4, 8);
  add(Wg1,             Wap, 100, 256, 4, 16);
  add(Wg1 + 100 * 256, Wbp, 100, 256, 4, 16);
  add(Wg2, Wg2p, 256, 256, 8, 16);
  add(Wg3, Wg3p, 256, 256, 8, 16);
  add(Wg4, Wg4p, 256, 256, 8, 16);
  add(Wf,  Wfp,  256, 256, 8, 16);
  add(Wo1, Wo1p, 256, 256, 8, 16);
  add(Wo2, Wo2p, 256, 10, 8, 1);
  pa.n_desc = nd;
  pa.total_tiles = tb;
  pa.pp_blocks = (tb * 64 + 255) / 256;
  // merged prepack + qb: one launch, qb runs concurrent with weight prepack
  prepack_all<<<pa.pp_blocks + 512, 256, 0, stream>>>(pa, qst, Wg1, bg1, qb);

  enc_kernel<<<1536, 256, 0, stream>>>(tabs, bi1, bi2, bi3, Wi1p, Wi2p, Wi3p, Wap, Wbp,
                                       qb, uq_g, v_g);
  pair_kernel<<<4096, 512, 0, stream>>>(uq_g, v_g, Wg2p, Wg3p, Wg4p, bg2, bg3, bg4, g_g);
  head_kernel<<<512, 256, 0, stream>>>(g_g, Wfp, bf_, Wo1p, bo1, Wo2p, bo2, outp);
}